// Round 14
// baseline (577.143 us; speedup 1.0000x reference)
//
#include <hip/hip_runtime.h>
#include <hip/hip_bf16.h>
#include <math.h>

// ---------------------------------------------------------------------------
// LIF layer, round 24 (= R23 resubmit; R13 bench was an infra failure, the
// kernel never ran). W PRE-SPLIT + direct-to-LDS B staging.
//
// R22 (wall 418.5): fused split+GEMM+scan; VALUBusy 30% from per-tile
// redundant Dekker conversion (A x16, W x32 blocks). R23/R24: W split ONCE
// (tiny kernel, ~24MB traffic; block 0 zeroes counters -> memset launch
// deleted), gemm stages B via global_load_lds (R15-proven path) into a
// 3-slot B ring; A keeps the fused reg-convert 2-slot ring. Per-step VMEM
// issue order fixed at {4 A-gloads, 2 B-glds} -> vmcnt(6) invariant
// UNCHANGED. B-slot hazard: slot written at kc was last read at kc-1,
// protected by the step-kc barrier. Main loop unrolled x6 (lcm 2,3) for
// static slots; tails kc=60..63 hand-derived. Wh/Wl = identical Dekker
// values -> C bitwise identical -> absmax 0.0.
// Cleanups vs R23 source: removed a dead UB-adjacent line in DEK8 and the
// unused STEP macro (no semantic change).
//
// Pipeline: k1 wsplit(W->Wh,Wl + zero counters) / k3 gemm+scan / k5 repair.
// Fallback (ws too small): R8 fused exact kernel.
// ---------------------------------------------------------------------------

typedef unsigned short u16;
typedef __attribute__((ext_vector_type(8))) short bf16x8;
typedef __attribute__((ext_vector_type(4))) float f32x4;

constexpr int T_STEPS = 64;
constexpr int BATCH   = 128;
constexpr int K_DIM   = 2048;
constexpr int N_DIM   = 2048;
constexpr int M_DIM   = T_STEPS * BATCH;      // 8192
constexpr int NCHAIN  = BATCH * N_DIM;        // 262144

constexpr float DECAY_F32 = (float)0.6065306597126334;
constexpr float BAND      = 2e-4f;            // error tail ~6e-5, 3.3x margin

#define GLDS16(g, l) __builtin_amdgcn_global_load_lds(                       \
    (const __attribute__((address_space(1))) void*)(g),                      \
    (__attribute__((address_space(3))) void*)(l), 16, 0, 0)

// ---------------------------------------------------------------------------
// k1: W -> bf16 hi/lo (Dekker), 8 elems/thread; block 0 zeroes counters.
// ---------------------------------------------------------------------------
__global__ __launch_bounds__(256)
void wsplit(const float* __restrict__ W, u16* __restrict__ Wh,
            u16* __restrict__ Wl, unsigned int* __restrict__ counters) {
    if (blockIdx.x == 0 && threadIdx.x < 128) counters[threadIdx.x] = 0u;
    const int base = blockIdx.x * 256 + threadIdx.x;
    const float4 v0 = *(const float4*)(W + (size_t)base * 8);
    const float4 v1 = *(const float4*)(W + (size_t)base * 8 + 4);
    const float f[8] = {v0.x, v0.y, v0.z, v0.w, v1.x, v1.y, v1.z, v1.w};
    unsigned int hp[4], lp[4];
#pragma unroll
    for (int q = 0; q < 8; q += 2) {
        u16 hh[2], ll[2];
#pragma unroll
        for (int e = 0; e < 2; e++) {
            __hip_bfloat16 hb = __float2bfloat16(f[q + e]);
            const float hf = __bfloat162float(hb);
            __hip_bfloat16 lb = __float2bfloat16(f[q + e] - hf);
            hh[e] = *(u16*)&hb;
            ll[e] = *(u16*)&lb;
        }
        hp[q >> 1] = (unsigned int)hh[0] | ((unsigned int)hh[1] << 16);
        lp[q >> 1] = (unsigned int)ll[0] | ((unsigned int)ll[1] << 16);
    }
    *(uint4*)(Wh + (size_t)base * 8) = make_uint4(hp[0], hp[1], hp[2], hp[3]);
    *(uint4*)(Wl + (size_t)base * 8) = make_uint4(lp[0], lp[1], lp[2], lp[3]);
}

// ---------------------------------------------------------------------------
// k3: fused split+GEMM+scan. bf16x3 (hh+hl+lh), tile = (64t x 4b) x 128o,
// 8 waves, BK=32. A: f32 gload -> reg Dekker -> 2-slot ds_write ring.
// B: pre-split Wh/Wl via global_load_lds -> 3-slot ring. Counted vmcnt(6).
// Epilogue: in-LDS LIF scan, spikes -> out, flagged chains -> worklist.
// ---------------------------------------------------------------------------
__global__ __launch_bounds__(512, 2)
void gemm_lif(const float* __restrict__ X,
              const u16* __restrict__ Bh, const u16* __restrict__ Bl,
              const float* __restrict__ bias, float* __restrict__ out,
              unsigned int* __restrict__ counters,
              unsigned int* __restrict__ worklist) {
    extern __shared__ __align__(16) u16 smem[];
    u16* const sAh = smem;                          // [2][8192] 32 KiB
    u16* const sAl = smem + 2 * 8192;               // [2][8192] 32 KiB
    u16* const sBh = smem + 4 * 8192;               // [3][4096] 24 KiB
    u16* const sBl = smem + 4 * 8192 + 3 * 4096;    // [3][4096] 24 KiB

    const int tid  = threadIdx.x;
    const int orig = blockIdx.x + gridDim.x * blockIdx.y;   // 0..511
    // XCD-chunked swizzle (bijective: 512 % 8 == 0)
    const int wg   = (orig & 7) * 64 + (orig >> 3);
    const int b0i  = (wg >> 4) * 4;     // batch base (4 b per tile)
    const int n0   = (wg & 15) * 128;   // output-channel base
    const int lane = tid & 63;
    const int wave = tid >> 6;     // 0..7
    const int wm   = wave >> 1;    // 0..3 (64-row slab)
    const int wn   = wave & 1;     // 0..1 (64-col slab)

    // staging entry: tile row re = (tid>>6)*16 + (tid&15), k-slot ((tid>>4)&3)*8
    // tile row r <-> global A row (r>>2)*128 + b0i + (r&3)   [t = r>>2, bl = r&3]
    const int re   = (tid >> 6) * 16 + (tid & 15);   // 0..127
    const int ks_e = ((tid >> 4) & 3) * 8;
    const size_t a0f = (size_t)((re >> 2) * 128 + b0i + (re & 3)) * K_DIM + ks_e;
    const size_t a1f = (size_t)(((re >> 2) + 32) * 128 + b0i + (re & 3)) * K_DIM + ks_e;
    const size_t b0f = (size_t)(n0 + re) * K_DIM + ks_e;
    const int wA0 = tid * 8;            // u16 offset within an A slot
    const int wA1 = 4096 + tid * 8;
    const int lB0 = wave * 512;         // wave-uniform B dest; HW adds lane*16B

    f32x4 acc[4][4];
#pragma unroll
    for (int i = 0; i < 4; i++)
#pragma unroll
        for (int j = 0; j < 4; j++) acc[i][j] = (f32x4){0.f, 0.f, 0.f, 0.f};

    float4 g0[4], g1[4];   // A only (4 float4/step)

#define GLOADA(SET, kc) do {                                                 \
        const size_t k_ = (size_t)(kc) * 32;                                 \
        g##SET[0] = *(const float4*)(X + a0f + k_);                          \
        g##SET[1] = *(const float4*)(X + a0f + k_ + 4);                      \
        g##SET[2] = *(const float4*)(X + a1f + k_);                          \
        g##SET[3] = *(const float4*)(X + a1f + k_ + 4);                      \
    } while (0)

#define GLDSB(bs, kc) do {                                                   \
        const size_t k_ = (size_t)(kc) * 32;                                 \
        GLDS16(Bh + b0f + k_, sBh + (bs) * 4096 + lB0);                      \
        GLDS16(Bl + b0f + k_, sBl + (bs) * 4096 + lB0);                      \
    } while (0)

#define DEK8(v0, v1, HI, LO) do {                                            \
        const float f_[8] = {v0.x, v0.y, v0.z, v0.w, v1.x, v1.y, v1.z, v1.w};\
        unsigned int hp_[4], lp_[4];                                         \
        _Pragma("unroll")                                                    \
        for (int q_ = 0; q_ < 8; q_ += 2) {                                  \
            u16 hh_[2], ll_[2];                                              \
            _Pragma("unroll")                                                \
            for (int e_ = 0; e_ < 2; e_++) {                                 \
                __hip_bfloat16 hb_ = __float2bfloat16(f_[q_ + e_]);          \
                const float hf_ = __bfloat162float(hb_);                     \
                __hip_bfloat16 lb_ = __float2bfloat16(f_[q_ + e_] - hf_);    \
                hh_[e_] = *(u16*)&hb_;                                       \
                ll_[e_] = *(u16*)&lb_;                                       \
            }                                                                \
            hp_[q_ >> 1] = (unsigned int)hh_[0] | ((unsigned int)hh_[1] << 16); \
            lp_[q_ >> 1] = (unsigned int)ll_[0] | ((unsigned int)ll_[1] << 16); \
        }                                                                    \
        HI = make_uint4(hp_[0], hp_[1], hp_[2], hp_[3]);                     \
        LO = make_uint4(lp_[0], lp_[1], lp_[2], lp_[3]);                     \
    } while (0)

#define CONVWA(s, SET) do {                                                  \
        uint4 hA0_, lA0_, hA1_, lA1_;                                        \
        DEK8(g##SET[0], g##SET[1], hA0_, lA0_);                              \
        DEK8(g##SET[2], g##SET[3], hA1_, lA1_);                              \
        *(uint4*)&sAh[(s) * 8192 + wA0] = hA0_;                              \
        *(uint4*)&sAl[(s) * 8192 + wA0] = lA0_;                              \
        *(uint4*)&sAh[(s) * 8192 + wA1] = hA1_;                              \
        *(uint4*)&sAl[(s) * 8192 + wA1] = lA1_;                              \
    } while (0)

#define COMPUTE(ra, rb) do {                                                 \
        bf16x8 fah[4], fal[4], fbh[4], fbl[4];                               \
        _Pragma("unroll")                                                    \
        for (int ti = 0; ti < 4; ti++) {                                     \
            const int ta = wm * 4 + ti;                                      \
            fah[ti] = *(const bf16x8*)&sAh[(ra) * 8192 + (ta * 64 + lane) * 8]; \
            fal[ti] = *(const bf16x8*)&sAl[(ra) * 8192 + (ta * 64 + lane) * 8]; \
        }                                                                    \
        _Pragma("unroll")                                                    \
        for (int tj = 0; tj < 4; tj++) {                                     \
            const int tb = wn * 4 + tj;                                      \
            fbh[tj] = *(const bf16x8*)&sBh[(rb) * 4096 + (tb * 64 + lane) * 8]; \
            fbl[tj] = *(const bf16x8*)&sBl[(rb) * 4096 + (tb * 64 + lane) * 8]; \
        }                                                                    \
        __builtin_amdgcn_s_setprio(1);                                       \
        _Pragma("unroll")                                                    \
        for (int ti = 0; ti < 4; ti++)                                       \
        _Pragma("unroll")                                                    \
        for (int tj = 0; tj < 4; tj++) {                                     \
            acc[ti][tj] = __builtin_amdgcn_mfma_f32_16x16x32_bf16(           \
                fah[ti], fbh[tj], acc[ti][tj], 0, 0, 0);                     \
            acc[ti][tj] = __builtin_amdgcn_mfma_f32_16x16x32_bf16(           \
                fah[ti], fbl[tj], acc[ti][tj], 0, 0, 0);                     \
            acc[ti][tj] = __builtin_amdgcn_mfma_f32_16x16x32_bf16(           \
                fal[ti], fbh[tj], acc[ti][tj], 0, 0, 0);                     \
        }                                                                    \
        __builtin_amdgcn_s_setprio(0);                                       \
    } while (0)

#define BAR do {                                                             \
        __builtin_amdgcn_sched_barrier(0);                                   \
        __builtin_amdgcn_s_barrier();                                        \
        __builtin_amdgcn_sched_barrier(0);                                   \
    } while (0)
#define VMW(n) do {                                                          \
        asm volatile("s_waitcnt vmcnt(" #n ")" ::: "memory");                \
        __builtin_amdgcn_sched_barrier(0);                                   \
    } while (0)
#define LGKM0 do {                                                           \
        asm volatile("s_waitcnt lgkmcnt(0)" ::: "memory");                   \
        __builtin_amdgcn_sched_barrier(0);                                   \
    } while (0)

    // prologue: A(0)->regs g0, B(0)->slot0 in flight; A(1)->g1, B(1)->slot1
    GLOADA(0, 0);
    GLDSB(0, 0);
    GLOADA(1, 1);
    GLDSB(1, 1);
    VMW(6);               // A(0) + B(0) landed (A(1)/B(1) = newest 6 in flight)
    CONVWA(0, 0);         // A slot0 <- g0(k0)
    LGKM0;

    // main loop: unrolled x6 (A ring mod 2, B ring mod 3), kcb = 0,6,...,54
    for (int kcb = 0; kcb < 60; kcb += 6) {
        // kc = kcb+0: read A0,B0; stage g0<-kc+2, Bslot2<-kc+2
        BAR;  GLOADA(0, kcb + 2);  GLDSB(2, kcb + 2);  VMW(6);
        CONVWA(1, 1);  LGKM0;  COMPUTE(0, 0);
        // kc = kcb+1: read A1,B1; stage g1<-kc+3, Bslot0<-kc+3
        BAR;  GLOADA(1, kcb + 3);  GLDSB(0, kcb + 3);  VMW(6);
        CONVWA(0, 0);  LGKM0;  COMPUTE(1, 1);
        // kc = kcb+2: read A0,B2
        BAR;  GLOADA(0, kcb + 4);  GLDSB(1, kcb + 4);  VMW(6);
        CONVWA(1, 1);  LGKM0;  COMPUTE(0, 2);
        // kc = kcb+3: read A1,B0
        BAR;  GLOADA(1, kcb + 5);  GLDSB(2, kcb + 5);  VMW(6);
        CONVWA(0, 0);  LGKM0;  COMPUTE(1, 0);
        // kc = kcb+4: read A0,B1
        BAR;  GLOADA(0, kcb + 6);  GLDSB(0, kcb + 6);  VMW(6);
        CONVWA(1, 1);  LGKM0;  COMPUTE(0, 1);
        // kc = kcb+5: read A1,B2
        BAR;  GLOADA(1, kcb + 7);  GLDSB(1, kcb + 7);  VMW(6);
        CONVWA(0, 0);  LGKM0;  COMPUTE(1, 2);
    }
    // kc = 60: read A0,B0; stage 62 -> g0/Bslot2
    BAR;  GLOADA(0, 62);  GLDSB(2, 62);  VMW(6);
    CONVWA(1, 1);  LGKM0;  COMPUTE(0, 0);
    // kc = 61: read A1,B1; stage 63 -> g1/Bslot0
    BAR;  GLOADA(1, 63);  GLDSB(0, 63);  VMW(6);
    CONVWA(0, 0);  LGKM0;  COMPUTE(1, 1);
    // kc = 62: read A0,B2; drain A(63)/B(63)
    BAR;  VMW(0);
    CONVWA(1, 1);  LGKM0;  COMPUTE(0, 2);
    // kc = 63: read A1,B0
    BAR;  COMPUTE(1, 0);

#undef LGKM0
#undef VMW
#undef BAR
#undef COMPUTE
#undef CONVWA
#undef DEK8
#undef GLDSB
#undef GLOADA

    // ------------------------------------------------------------------
    // epilogue: reuse smem as cur[256][129] f32 (132096 B), in-LDS scan.
    // ------------------------------------------------------------------
    __syncthreads();                    // all ring reads done, smem reusable
    float* const curL = (float*)smem;

#pragma unroll
    for (int tj = 0; tj < 4; tj++) {
        const int col = wn * 64 + tj * 16 + (lane & 15);
        const float bv = bias[n0 + col];
#pragma unroll
        for (int ti = 0; ti < 4; ti++) {
            const int rb = wm * 64 + ti * 16 + (lane >> 4) * 4;
#pragma unroll
            for (int r = 0; r < 4; r++)
                curL[(rb + r) * 129 + col] = acc[ti][tj][r] + bv;
        }
    }
    __syncthreads();                    // cur tile complete

    // scan: 512 threads = 512 chains (bl = tid>>7, col = tid&127)
    {
        const int bl  = tid >> 7;
        const int col = tid & 127;
        const int b   = b0i + bl;
        const int o   = n0 + col;
        float mem = 0.0f;
        bool flag = false;
#pragma unroll
        for (int t = 0; t < T_STEPS; t++) {
            const float cv = curL[(t * 4 + bl) * 129 + col];
            mem = __fadd_rn(__fmul_rn(mem, DECAY_F32), cv);
            const float d = __fsub_rn(mem, 1.0f);
            const bool spk = d > 0.0f;
            if (fabsf(d) < BAND) flag = true;
            out[(size_t)t * NCHAIN + (size_t)b * N_DIM + o] = spk ? 1.0f : 0.0f;
            if (spk) mem = __fsub_rn(mem, 1.0f);
        }
        if (flag) {
            const unsigned int p = atomicAdd(&counters[b], 1u);
            worklist[b * 2048 + p] = (unsigned int)o;
        }
    }
}

// ---------------------------------------------------------------------------
// k5: b-grouped exact repair + register-staged chunk double-buffer (R21).
// ---------------------------------------------------------------------------
#define RG 16    // chains per group
#define RJ 4     // block-strides per b
#define BKR 64   // k-chunk (320 = 5*64: panel boundaries land on chunk edges)

__global__ __launch_bounds__(256)
void lif_repair2(const float* __restrict__ X, const float* __restrict__ W,
                 const float* __restrict__ bias,
                 const unsigned int* __restrict__ counters,
                 const unsigned int* __restrict__ worklist,
                 float* __restrict__ out) {
    __shared__ float sX[BKR][T_STEPS + 1];      // [k][t] 16.25 KiB
    __shared__ float sW[RG][BKR + 1];           // [o][k]  4.06 KiB
    __shared__ float scur[T_STEPS][RG + 1];
    __shared__ float sspk[T_STEPS][RG + 1];
    __shared__ int   so[RG];

    const int b = blockIdx.x / RJ;
    const int j = blockIdx.x % RJ;
    const unsigned int n_b = counters[b];
    if (n_b == 0) return;
    const int ngroups = (int)(n_b + RG - 1) / RG;

    const int tid = threadIdx.x;
    const int t   = tid & 63;
    const int oi  = tid >> 6;          // 0..3, owns o-slots 4*oi .. 4*oi+3

    const int ts  = tid >> 2;          // X row 0..63
    const int kq  = (tid & 3) * 16;    // X col quarter
    const int wo  = tid >> 4;          // W row 0..15
    const int wkq = (tid & 15) * 4;    // W col quad

    for (int g = j; g < ngroups; g += RJ) {
        if (tid < RG) {
            const int slot = g * RG + tid;
            so[tid] = (slot < (int)n_b) ? (int)worklist[b * 2048 + slot] : -1;
        }
        __syncthreads();

        float Csum[4] = {0.f, 0.f, 0.f, 0.f};
        float P[4]    = {0.f, 0.f, 0.f, 0.f};

        float4 rx[4];
        float4 rw;
        {
            const float* srcx = &X[(size_t)(ts * BATCH + b) * K_DIM + kq];
#pragma unroll
            for (int q = 0; q < 4; q++) rx[q] = *(const float4*)(srcx + q * 4);
            const int o = so[wo];
            rw = (o >= 0) ? *(const float4*)&W[(size_t)o * K_DIM + wkq]
                          : make_float4(0.f, 0.f, 0.f, 0.f);
        }

        for (int c = 0; c < K_DIM / BKR; c++) {
            if (c > 0 && (c % 5) == 0) {       // k = 320*j panel boundary
#pragma unroll
                for (int q = 0; q < 4; q++) {
                    Csum[q] = __fadd_rn(Csum[q], P[q]);
                    P[q] = 0.f;
                }
            }
            __syncthreads();                   // prev chunk's LDS reads done
#pragma unroll
            for (int q = 0; q < 4; q++) {
                sX[kq + q * 4 + 0][ts] = rx[q].x;
                sX[kq + q * 4 + 1][ts] = rx[q].y;
                sX[kq + q * 4 + 2][ts] = rx[q].z;
                sX[kq + q * 4 + 3][ts] = rx[q].w;
            }
            sW[wo][wkq + 0] = rw.x; sW[wo][wkq + 1] = rw.y;
            sW[wo][wkq + 2] = rw.z; sW[wo][wkq + 3] = rw.w;
            if (c + 1 < K_DIM / BKR) {
                const int k1 = (c + 1) * BKR;
                const float* srcx = &X[(size_t)(ts * BATCH + b) * K_DIM + k1 + kq];
#pragma unroll
                for (int q = 0; q < 4; q++) rx[q] = *(const float4*)(srcx + q * 4);
                const int o = so[wo];
                rw = (o >= 0) ? *(const float4*)&W[(size_t)o * K_DIM + k1 + wkq]
                              : make_float4(0.f, 0.f, 0.f, 0.f);
            }
            __syncthreads();                   // LDS chunk c ready
#pragma unroll 8
            for (int k = 0; k < BKR; k++) {
                const float xv = sX[k][t];
#pragma unroll
                for (int q = 0; q < 4; q++)
                    P[q] = fmaf(xv, sW[oi * 4 + q][k], P[q]);
            }
        }
        __syncthreads();
#pragma unroll
        for (int q = 0; q < 4; q++) {
            Csum[q] = __fadd_rn(Csum[q], P[q]);    // final 128-elem panel
            const int o = so[oi * 4 + q];
            scur[t][oi * 4 + q] = (o >= 0) ? __fadd_rn(Csum[q], bias[o]) : 0.f;
        }
        __syncthreads();
        if (tid < RG && so[tid] >= 0) {
            float mem = 0.0f;
            for (int tt = 0; tt < T_STEPS; tt++) {
                mem = __fadd_rn(__fmul_rn(mem, DECAY_F32), scur[tt][tid]);
                const float d = __fsub_rn(mem, 1.0f);
                const bool spk = d > 0.0f;
                sspk[tt][tid] = spk ? 1.0f : 0.0f;
                if (spk) mem = __fsub_rn(mem, 1.0f);
            }
        }
        __syncthreads();
#pragma unroll
        for (int q = 0; q < 4; q++) {
            const int o = so[oi * 4 + q];
            if (o >= 0)
                out[(size_t)t * NCHAIN + (size_t)b * N_DIM + o] = sspk[t][oi * 4 + q];
        }
        __syncthreads();
    }
}

// ---------------------------------------------------------------------------
// FALLBACK (R8, known-passing, ws-free).
// ---------------------------------------------------------------------------
__global__ __launch_bounds__(256)
void lif_openblas_q320(const float* __restrict__ X, const float* __restrict__ W,
                       const float* __restrict__ bias, float* __restrict__ out) {
    __shared__ float As[16][T_STEPS + 4];
    __shared__ float Ws[16][64 + 4];
    __shared__ float curbuf[T_STEPS][64 + 1];
    const int tid = threadIdx.x;
    const int o0 = blockIdx.x * 64, b0 = blockIdx.y;
    const int tm = (tid & 15) * 4, tn = (tid >> 4) * 4;
    float Csum[4][4], Pacc[4][4];
#pragma unroll
    for (int i = 0; i < 4; i++)
#pragma unroll
        for (int j = 0; j < 4; j++) { Csum[i][j] = 0.f; Pacc[i][j] = 0.f; }
    for (int c = 0; c < K_DIM / 16; c++) {
        if (c > 0 && (c % 20) == 0) {
#pragma unroll
            for (int i = 0; i < 4; i++)
#pragma unroll
                for (int j = 0; j < 4; j++) {
                    Csum[i][j] = __fadd_rn(Csum[i][j], Pacc[i][j]);
                    Pacc[i][j] = 0.f;
                }
        }
        const int k0 = c * 16;
        {
            const int t = tid >> 2, kq = (tid & 3) * 4;
            const float4 av = *(const float4*)&X[(size_t)(t * BATCH + b0) * K_DIM + k0 + kq];
            As[kq + 0][t] = av.x; As[kq + 1][t] = av.y;
            As[kq + 2][t] = av.z; As[kq + 3][t] = av.w;
            const float4 wv = *(const float4*)&W[(size_t)(o0 + t) * K_DIM + k0 + kq];
            Ws[kq + 0][t] = wv.x; Ws[kq + 1][t] = wv.y;
            Ws[kq + 2][t] = wv.z; Ws[kq + 3][t] = wv.w;
        }
        __syncthreads();
#pragma unroll
        for (int k = 0; k < 16; k++) {
            float a[4], w[4];
#pragma unroll
            for (int i = 0; i < 4; i++) a[i] = As[k][tm + i];
#pragma unroll
            for (int j = 0; j < 4; j++) w[j] = Ws[k][tn + j];
#pragma unroll
            for (int i = 0; i < 4; i++)
#pragma unroll
                for (int j = 0; j < 4; j++) Pacc[i][j] = fmaf(a[i], w[j], Pacc[i][j]);
        }
        __syncthreads();
    }
#pragma unroll
    for (int i = 0; i < 4; i++)
#pragma unroll
        for (int j = 0; j < 4; j++)
            curbuf[tm + i][tn + j] =
                __fadd_rn(__fadd_rn(Csum[i][j], Pacc[i][j]), bias[o0 + tn + j]);
    __syncthreads();
    if (tid < 64) {
        float mem = 0.0f;
#pragma unroll
        for (int t = 0; t < T_STEPS; t++) {
            mem = __fadd_rn(__fmul_rn(mem, DECAY_F32), curbuf[t][tid]);
            const float d = __fsub_rn(mem, 1.0f);
            const bool spk = d > 0.0f;
            out[(size_t)t * NCHAIN + (size_t)b0 * N_DIM + o0 + tid] = spk ? 1.0f : 0.0f;
            if (spk) mem = __fsub_rn(mem, 1.0f);
        }
    }
}

extern "C" void kernel_launch(void* const* d_in, const int* in_sizes, int n_in,
                              void* d_out, int out_size, void* d_ws, size_t ws_size,
                              hipStream_t stream) {
    const float* x = nullptr; const float* W = nullptr; const float* bias = nullptr;
    for (int i = 0; i < n_in; i++) {
        if      (in_sizes[i] == M_DIM * K_DIM) x    = (const float*)d_in[i];
        else if (in_sizes[i] == N_DIM * K_DIM) W    = (const float*)d_in[i];
        else if (in_sizes[i] == N_DIM)         bias = (const float*)d_in[i];
    }
    if (!x)    x    = (const float*)d_in[0];
    if (!W)    W    = (const float*)d_in[1];
    if (!bias) bias = (const float*)d_in[2];
    float* out = (float*)d_out;

    // workspace layout: counters + worklist + Wh + Wl
    const size_t off_cnt = 0;                                   // 128 u32
    const size_t off_wl  = 512;                                 // 128*2048 u32
    const size_t off_Wh  = off_wl + (size_t)128 * 2048 * 4;     // 1049088
    const size_t szW     = (size_t)N_DIM * K_DIM * 2;           // 8 MiB
    const size_t off_Wl  = off_Wh + szW;
    const size_t need    = off_Wl + szW;                        // ~17.8 MB

    if (ws_size < need) {
        dim3 grid(N_DIM / 64, BATCH);
        lif_openblas_q320<<<grid, 256, 0, stream>>>(x, W, bias, out);
        return;
    }

    char* ws = (char*)d_ws;
    unsigned int* counters = (unsigned int*)(ws + off_cnt);
    unsigned int* worklist = (unsigned int*)(ws + off_wl);
    u16* Wh = (u16*)(ws + off_Wh);
    u16* Wl = (u16*)(ws + off_Wl);

    wsplit<<<(N_DIM * K_DIM / 8) / 256, 256, 0, stream>>>(W, Wh, Wl, counters);
    dim3 ggrid(N_DIM / 128, M_DIM / 256);   // (16, 32) -> 512 tiles
    gemm_lif<<<ggrid, 512, 132096, stream>>>(x, Wh, Wl, bias, out, counters, worklist);
    lif_repair2<<<128 * RJ, 256, 0, stream>>>(x, W, bias, counters, worklist, out);
}

// Round 15
// 566.214 us; speedup vs baseline: 1.0193x; 1.0193x over previous
//
#include <hip/hip_runtime.h>
#include <hip/hip_bf16.h>
#include <math.h>

// ---------------------------------------------------------------------------
// LIF layer, round 25: R22 structure restored (2-slot ring, 2-step loop,
// vmcnt(6)) + W pre-split applied MINIMALLY: B loads pre-split u16 (2 uint4
// per step, same 8 elements, same VMEM count) -> direct LDS store, no B
// conversion in the hot loop.
//
// R24 post-mortem: x6-unrolled loop + mixed gload_lds queue = uniform 1.7x
// slowdown (MfmaUtil 37->21, VALUBusy 30->15.5, FETCH unchanged) — code
// footprint / scheduler stall, not memory. Reverted to the 2-step body that
// benched 239.5us in R20/R22. This round's only delta vs R22: B stream is
// pre-split (wsplit kernel, ~24MB, also zeroes counters -> memset launch
// gone); per-step VMEM stays {4 A-float4, 2 B-uint4} = 6 -> vmcnt(6)
// invariant identical; per-step DEK8 count 6 -> 4. Wh/Wl = identical Dekker
// values -> C bitwise identical -> absmax 0.0.
//
// Pipeline: k1 wsplit(W->Wh,Wl + zero counters) / k3 gemm+scan / k5 repair.
// Fallback (ws too small): R8 fused exact kernel.
// ---------------------------------------------------------------------------

typedef unsigned short u16;
typedef __attribute__((ext_vector_type(8))) short bf16x8;
typedef __attribute__((ext_vector_type(4))) float f32x4;

constexpr int T_STEPS = 64;
constexpr int BATCH   = 128;
constexpr int K_DIM   = 2048;
constexpr int N_DIM   = 2048;
constexpr int M_DIM   = T_STEPS * BATCH;      // 8192
constexpr int NCHAIN  = BATCH * N_DIM;        // 262144

constexpr float DECAY_F32 = (float)0.6065306597126334;
constexpr float BAND      = 2e-4f;            // error tail ~6e-5, 3.3x margin

// ---------------------------------------------------------------------------
// k1: W -> bf16 hi/lo (Dekker), 8 elems/thread; block 0 zeroes counters.
// (Ran correctly in R24: absmax 0.0.)
// ---------------------------------------------------------------------------
__global__ __launch_bounds__(256)
void wsplit(const float* __restrict__ W, u16* __restrict__ Wh,
            u16* __restrict__ Wl, unsigned int* __restrict__ counters) {
    if (blockIdx.x == 0 && threadIdx.x < 128) counters[threadIdx.x] = 0u;
    const int base = blockIdx.x * 256 + threadIdx.x;
    const float4 v0 = *(const float4*)(W + (size_t)base * 8);
    const float4 v1 = *(const float4*)(W + (size_t)base * 8 + 4);
    const float f[8] = {v0.x, v0.y, v0.z, v0.w, v1.x, v1.y, v1.z, v1.w};
    unsigned int hp[4], lp[4];
#pragma unroll
    for (int q = 0; q < 8; q += 2) {
        u16 hh[2], ll[2];
#pragma unroll
        for (int e = 0; e < 2; e++) {
            __hip_bfloat16 hb = __float2bfloat16(f[q + e]);
            const float hf = __bfloat162float(hb);
            __hip_bfloat16 lb = __float2bfloat16(f[q + e] - hf);
            hh[e] = *(u16*)&hb;
            ll[e] = *(u16*)&lb;
        }
        hp[q >> 1] = (unsigned int)hh[0] | ((unsigned int)hh[1] << 16);
        lp[q >> 1] = (unsigned int)ll[0] | ((unsigned int)ll[1] << 16);
    }
    *(uint4*)(Wh + (size_t)base * 8) = make_uint4(hp[0], hp[1], hp[2], hp[3]);
    *(uint4*)(Wl + (size_t)base * 8) = make_uint4(lp[0], lp[1], lp[2], lp[3]);
}

// ---------------------------------------------------------------------------
// k3: fused GEMM+scan. bf16x3 (hh+hl+lh), tile = (64t x 4b) x 128o, 8 waves,
// BK=32, 2-slot LDS ring (96 KiB), XCD swizzle, counted vmcnt (R22 verbatim
// structure). A: f32 gload -> reg Dekker -> ds_write. B: pre-split u16
// gload -> direct ds_write. Epilogue: in-LDS LIF scan.
// ---------------------------------------------------------------------------
__global__ __launch_bounds__(512, 2)
void gemm_lif(const float* __restrict__ X,
              const u16* __restrict__ Bh, const u16* __restrict__ Bl,
              const float* __restrict__ bias, float* __restrict__ out,
              unsigned int* __restrict__ counters,
              unsigned int* __restrict__ worklist) {
    extern __shared__ __align__(16) u16 smem[];
    u16* const sAh = smem;                          // [2][8192] 32 KiB
    u16* const sAl = smem + 2 * 8192;               // [2][8192] 32 KiB
    u16* const sBh = smem + 4 * 8192;               // [2][4096] 16 KiB
    u16* const sBl = smem + 4 * 8192 + 2 * 4096;    // [2][4096] 16 KiB

    const int tid  = threadIdx.x;
    const int orig = blockIdx.x + gridDim.x * blockIdx.y;   // 0..511
    // XCD-chunked swizzle (bijective: 512 % 8 == 0)
    const int wg   = (orig & 7) * 64 + (orig >> 3);
    const int b0i  = (wg >> 4) * 4;     // batch base (4 b per tile)
    const int n0   = (wg & 15) * 128;   // output-channel base
    const int lane = tid & 63;
    const int wave = tid >> 6;     // 0..7
    const int wm   = wave >> 1;    // 0..3 (64-row slab)
    const int wn   = wave & 1;     // 0..1 (64-col slab)

    // staging entry: tile row re = (tid>>6)*16 + (tid&15), k-slot ((tid>>4)&3)*8
    // tile row r <-> global A row (r>>2)*128 + b0i + (r&3)   [t = r>>2, bl = r&3]
    const int re   = (tid >> 6) * 16 + (tid & 15);   // 0..127
    const int ks_e = ((tid >> 4) & 3) * 8;
    const size_t a0f = (size_t)((re >> 2) * 128 + b0i + (re & 3)) * K_DIM + ks_e;
    const size_t a1f = (size_t)(((re >> 2) + 32) * 128 + b0i + (re & 3)) * K_DIM + ks_e;
    const size_t b0f = (size_t)(n0 + re) * K_DIM + ks_e;   // u16 element index
    const int wA0 = tid * 8;            // u16 offset within an A slot
    const int wA1 = 4096 + tid * 8;
    const int wB0 = tid * 8;            // u16 offset within a B slot

    f32x4 acc[4][4];
#pragma unroll
    for (int i = 0; i < 4; i++)
#pragma unroll
        for (int j = 0; j < 4; j++) acc[i][j] = (f32x4){0.f, 0.f, 0.f, 0.f};

    float4 ga0[4], ga1[4];   // A f32 (4 float4/step)
    uint4  gb0[2], gb1[2];   // B pre-split u16 (2 uint4/step: hi, lo)

#define GLOAD(SET, kc) do {                                                  \
        const size_t k_ = (size_t)(kc) * 32;                                 \
        ga##SET[0] = *(const float4*)(X + a0f + k_);                         \
        ga##SET[1] = *(const float4*)(X + a0f + k_ + 4);                     \
        ga##SET[2] = *(const float4*)(X + a1f + k_);                         \
        ga##SET[3] = *(const float4*)(X + a1f + k_ + 4);                     \
        gb##SET[0] = *(const uint4*)(Bh + b0f + k_);                         \
        gb##SET[1] = *(const uint4*)(Bl + b0f + k_);                         \
    } while (0)

#define DEK8(v0, v1, HI, LO) do {                                            \
        const float f_[8] = {v0.x, v0.y, v0.z, v0.w, v1.x, v1.y, v1.z, v1.w};\
        unsigned int hp_[4], lp_[4];                                         \
        _Pragma("unroll")                                                    \
        for (int q_ = 0; q_ < 8; q_ += 2) {                                  \
            u16 hh_[2], ll_[2];                                              \
            _Pragma("unroll")                                                \
            for (int e_ = 0; e_ < 2; e_++) {                                 \
                __hip_bfloat16 hb_ = __float2bfloat16(f_[q_ + e_]);          \
                const float hf_ = __bfloat162float(hb_);                     \
                __hip_bfloat16 lb_ = __float2bfloat16(f_[q_ + e_] - hf_);    \
                hh_[e_] = *(u16*)&hb_;                                       \
                ll_[e_] = *(u16*)&lb_;                                       \
            }                                                                \
            hp_[q_ >> 1] = (unsigned int)hh_[0] | ((unsigned int)hh_[1] << 16); \
            lp_[q_ >> 1] = (unsigned int)ll_[0] | ((unsigned int)ll_[1] << 16); \
        }                                                                    \
        HI = make_uint4(hp_[0], hp_[1], hp_[2], hp_[3]);                     \
        LO = make_uint4(lp_[0], lp_[1], lp_[2], lp_[3]);                     \
    } while (0)

#define CONVWRITE(s, SET) do {                                               \
        uint4 hA0_, lA0_, hA1_, lA1_;                                        \
        DEK8(ga##SET[0], ga##SET[1], hA0_, lA0_);                            \
        DEK8(ga##SET[2], ga##SET[3], hA1_, lA1_);                            \
        *(uint4*)&sAh[(s) * 8192 + wA0] = hA0_;                              \
        *(uint4*)&sAl[(s) * 8192 + wA0] = lA0_;                              \
        *(uint4*)&sAh[(s) * 8192 + wA1] = hA1_;                              \
        *(uint4*)&sAl[(s) * 8192 + wA1] = lA1_;                              \
        *(uint4*)&sBh[(s) * 4096 + wB0] = gb##SET[0];                        \
        *(uint4*)&sBl[(s) * 4096 + wB0] = gb##SET[1];                        \
    } while (0)

#define COMPUTE(rs) do {                                                     \
        bf16x8 fah[4], fal[4], fbh[4], fbl[4];                               \
        _Pragma("unroll")                                                    \
        for (int ti = 0; ti < 4; ti++) {                                     \
            const int ta = wm * 4 + ti;                                      \
            fah[ti] = *(const bf16x8*)&sAh[(rs) * 8192 + (ta * 64 + lane) * 8]; \
            fal[ti] = *(const bf16x8*)&sAl[(rs) * 8192 + (ta * 64 + lane) * 8]; \
        }                                                                    \
        _Pragma("unroll")                                                    \
        for (int tj = 0; tj < 4; tj++) {                                     \
            const int tb = wn * 4 + tj;                                      \
            fbh[tj] = *(const bf16x8*)&sBh[(rs) * 4096 + (tb * 64 + lane) * 8]; \
            fbl[tj] = *(const bf16x8*)&sBl[(rs) * 4096 + (tb * 64 + lane) * 8]; \
        }                                                                    \
        __builtin_amdgcn_s_setprio(1);                                       \
        _Pragma("unroll")                                                    \
        for (int ti = 0; ti < 4; ti++)                                       \
        _Pragma("unroll")                                                    \
        for (int tj = 0; tj < 4; tj++) {                                     \
            acc[ti][tj] = __builtin_amdgcn_mfma_f32_16x16x32_bf16(           \
                fah[ti], fbh[tj], acc[ti][tj], 0, 0, 0);                     \
            acc[ti][tj] = __builtin_amdgcn_mfma_f32_16x16x32_bf16(           \
                fah[ti], fbl[tj], acc[ti][tj], 0, 0, 0);                     \
            acc[ti][tj] = __builtin_amdgcn_mfma_f32_16x16x32_bf16(           \
                fal[ti], fbh[tj], acc[ti][tj], 0, 0, 0);                     \
        }                                                                    \
        __builtin_amdgcn_s_setprio(0);                                       \
    } while (0)

#define BAR do {                                                             \
        __builtin_amdgcn_sched_barrier(0);                                   \
        __builtin_amdgcn_s_barrier();                                        \
        __builtin_amdgcn_sched_barrier(0);                                   \
    } while (0)
#define VMW(n) do {                                                          \
        asm volatile("s_waitcnt vmcnt(" #n ")" ::: "memory");                \
        __builtin_amdgcn_sched_barrier(0);                                   \
    } while (0)
#define LGKM0 do {                                                           \
        asm volatile("s_waitcnt lgkmcnt(0)" ::: "memory");                   \
        __builtin_amdgcn_sched_barrier(0);                                   \
    } while (0)

    // prologue: G(0) -> slot 0; G(1) in flight (R22 verbatim)
    GLOAD(0, 0);
    VMW(0);
    CONVWRITE(0, 0);
    GLOAD(1, 1);
    LGKM0;

    // main loop: even/odd bodies, GLOADs reach kc+2 = 61 (R22 verbatim)
    for (int kc = 0; kc < 60; kc += 2) {
        BAR;
        GLOAD(0, kc + 2);
        VMW(6);
        CONVWRITE(1, 1);
        LGKM0;
        COMPUTE(0);
        BAR;
        GLOAD(1, kc + 3);
        VMW(6);
        CONVWRITE(0, 0);
        LGKM0;
        COMPUTE(1);
    }
    BAR;
    GLOAD(0, 62);
    VMW(6);
    CONVWRITE(1, 1);
    LGKM0;
    COMPUTE(0);
    BAR;
    GLOAD(1, 63);
    VMW(6);
    CONVWRITE(0, 0);
    LGKM0;
    COMPUTE(1);
    BAR;
    VMW(0);
    CONVWRITE(1, 1);
    LGKM0;
    COMPUTE(0);
    BAR;
    COMPUTE(1);

#undef LGKM0
#undef VMW
#undef BAR
#undef COMPUTE
#undef CONVWRITE
#undef DEK8
#undef GLOAD

    // ------------------------------------------------------------------
    // epilogue: reuse smem as cur[256][129] f32 (132096 B), in-LDS scan.
    // (R22 verbatim)
    // ------------------------------------------------------------------
    __syncthreads();                    // all ring reads done, smem reusable
    float* const curL = (float*)smem;

#pragma unroll
    for (int tj = 0; tj < 4; tj++) {
        const int col = wn * 64 + tj * 16 + (lane & 15);
        const float bv = bias[n0 + col];
#pragma unroll
        for (int ti = 0; ti < 4; ti++) {
            const int rb = wm * 64 + ti * 16 + (lane >> 4) * 4;
#pragma unroll
            for (int r = 0; r < 4; r++)
                curL[(rb + r) * 129 + col] = acc[ti][tj][r] + bv;
        }
    }
    __syncthreads();                    // cur tile complete

    // scan: 512 threads = 512 chains (bl = tid>>7, col = tid&127)
    {
        const int bl  = tid >> 7;
        const int col = tid & 127;
        const int b   = b0i + bl;
        const int o   = n0 + col;
        float mem = 0.0f;
        bool flag = false;
#pragma unroll
        for (int t = 0; t < T_STEPS; t++) {
            const float cv = curL[(t * 4 + bl) * 129 + col];
            mem = __fadd_rn(__fmul_rn(mem, DECAY_F32), cv);
            const float d = __fsub_rn(mem, 1.0f);
            const bool spk = d > 0.0f;
            if (fabsf(d) < BAND) flag = true;
            out[(size_t)t * NCHAIN + (size_t)b * N_DIM + o] = spk ? 1.0f : 0.0f;
            if (spk) mem = __fsub_rn(mem, 1.0f);
        }
        if (flag) {
            const unsigned int p = atomicAdd(&counters[b], 1u);
            worklist[b * 2048 + p] = (unsigned int)o;
        }
    }
}

// ---------------------------------------------------------------------------
// k5: b-grouped exact repair + register-staged chunk double-buffer (R21).
// ---------------------------------------------------------------------------
#define RG 16    // chains per group
#define RJ 4     // block-strides per b
#define BKR 64   // k-chunk (320 = 5*64: panel boundaries land on chunk edges)

__global__ __launch_bounds__(256)
void lif_repair2(const float* __restrict__ X, const float* __restrict__ W,
                 const float* __restrict__ bias,
                 const unsigned int* __restrict__ counters,
                 const unsigned int* __restrict__ worklist,
                 float* __restrict__ out) {
    __shared__ float sX[BKR][T_STEPS + 1];      // [k][t] 16.25 KiB
    __shared__ float sW[RG][BKR + 1];           // [o][k]  4.06 KiB
    __shared__ float scur[T_STEPS][RG + 1];
    __shared__ float sspk[T_STEPS][RG + 1];
    __shared__ int   so[RG];

    const int b = blockIdx.x / RJ;
    const int j = blockIdx.x % RJ;
    const unsigned int n_b = counters[b];
    if (n_b == 0) return;
    const int ngroups = (int)(n_b + RG - 1) / RG;

    const int tid = threadIdx.x;
    const int t   = tid & 63;
    const int oi  = tid >> 6;          // 0..3, owns o-slots 4*oi .. 4*oi+3

    const int ts  = tid >> 2;          // X row 0..63
    const int kq  = (tid & 3) * 16;    // X col quarter
    const int wo  = tid >> 4;          // W row 0..15
    const int wkq = (tid & 15) * 4;    // W col quad

    for (int g = j; g < ngroups; g += RJ) {
        if (tid < RG) {
            const int slot = g * RG + tid;
            so[tid] = (slot < (int)n_b) ? (int)worklist[b * 2048 + slot] : -1;
        }
        __syncthreads();

        float Csum[4] = {0.f, 0.f, 0.f, 0.f};
        float P[4]    = {0.f, 0.f, 0.f, 0.f};

        float4 rx[4];
        float4 rw;
        {
            const float* srcx = &X[(size_t)(ts * BATCH + b) * K_DIM + kq];
#pragma unroll
            for (int q = 0; q < 4; q++) rx[q] = *(const float4*)(srcx + q * 4);
            const int o = so[wo];
            rw = (o >= 0) ? *(const float4*)&W[(size_t)o * K_DIM + wkq]
                          : make_float4(0.f, 0.f, 0.f, 0.f);
        }

        for (int c = 0; c < K_DIM / BKR; c++) {
            if (c > 0 && (c % 5) == 0) {       // k = 320*j panel boundary
#pragma unroll
                for (int q = 0; q < 4; q++) {
                    Csum[q] = __fadd_rn(Csum[q], P[q]);
                    P[q] = 0.f;
                }
            }
            __syncthreads();                   // prev chunk's LDS reads done
#pragma unroll
            for (int q = 0; q < 4; q++) {
                sX[kq + q * 4 + 0][ts] = rx[q].x;
                sX[kq + q * 4 + 1][ts] = rx[q].y;
                sX[kq + q * 4 + 2][ts] = rx[q].z;
                sX[kq + q * 4 + 3][ts] = rx[q].w;
            }
            sW[wo][wkq + 0] = rw.x; sW[wo][wkq + 1] = rw.y;
            sW[wo][wkq + 2] = rw.z; sW[wo][wkq + 3] = rw.w;
            if (c + 1 < K_DIM / BKR) {
                const int k1 = (c + 1) * BKR;
                const float* srcx = &X[(size_t)(ts * BATCH + b) * K_DIM + k1 + kq];
#pragma unroll
                for (int q = 0; q < 4; q++) rx[q] = *(const float4*)(srcx + q * 4);
                const int o = so[wo];
                rw = (o >= 0) ? *(const float4*)&W[(size_t)o * K_DIM + k1 + wkq]
                              : make_float4(0.f, 0.f, 0.f, 0.f);
            }
            __syncthreads();                   // LDS chunk c ready
#pragma unroll 8
            for (int k = 0; k < BKR; k++) {
                const float xv = sX[k][t];
#pragma unroll
                for (int q = 0; q < 4; q++)
                    P[q] = fmaf(xv, sW[oi * 4 + q][k], P[q]);
            }
        }
        __syncthreads();
#pragma unroll
        for (int q = 0; q < 4; q++) {
            Csum[q] = __fadd_rn(Csum[q], P[q]);    // final 128-elem panel
            const int o = so[oi * 4 + q];
            scur[t][oi * 4 + q] = (o >= 0) ? __fadd_rn(Csum[q], bias[o]) : 0.f;
        }
        __syncthreads();
        if (tid < RG && so[tid] >= 0) {
            float mem = 0.0f;
            for (int tt = 0; tt < T_STEPS; tt++) {
                mem = __fadd_rn(__fmul_rn(mem, DECAY_F32), scur[tt][tid]);
                const float d = __fsub_rn(mem, 1.0f);
                const bool spk = d > 0.0f;
                sspk[tt][tid] = spk ? 1.0f : 0.0f;
                if (spk) mem = __fsub_rn(mem, 1.0f);
            }
        }
        __syncthreads();
#pragma unroll
        for (int q = 0; q < 4; q++) {
            const int o = so[oi * 4 + q];
            if (o >= 0)
                out[(size_t)t * NCHAIN + (size_t)b * N_DIM + o] = sspk[t][oi * 4 + q];
        }
        __syncthreads();
    }
}

// ---------------------------------------------------------------------------
// FALLBACK (R8, known-passing, ws-free).
// ---------------------------------------------------------------------------
__global__ __launch_bounds__(256)
void lif_openblas_q320(const float* __restrict__ X, const float* __restrict__ W,
                       const float* __restrict__ bias, float* __restrict__ out) {
    __shared__ float As[16][T_STEPS + 4];
    __shared__ float Ws[16][64 + 4];
    __shared__ float curbuf[T_STEPS][64 + 1];
    const int tid = threadIdx.x;
    const int o0 = blockIdx.x * 64, b0 = blockIdx.y;
    const int tm = (tid & 15) * 4, tn = (tid >> 4) * 4;
    float Csum[4][4], Pacc[4][4];
#pragma unroll
    for (int i = 0; i < 4; i++)
#pragma unroll
        for (int j = 0; j < 4; j++) { Csum[i][j] = 0.f; Pacc[i][j] = 0.f; }
    for (int c = 0; c < K_DIM / 16; c++) {
        if (c > 0 && (c % 20) == 0) {
#pragma unroll
            for (int i = 0; i < 4; i++)
#pragma unroll
                for (int j = 0; j < 4; j++) {
                    Csum[i][j] = __fadd_rn(Csum[i][j], Pacc[i][j]);
                    Pacc[i][j] = 0.f;
                }
        }
        const int k0 = c * 16;
        {
            const int t = tid >> 2, kq = (tid & 3) * 4;
            const float4 av = *(const float4*)&X[(size_t)(t * BATCH + b0) * K_DIM + k0 + kq];
            As[kq + 0][t] = av.x; As[kq + 1][t] = av.y;
            As[kq + 2][t] = av.z; As[kq + 3][t] = av.w;
            const float4 wv = *(const float4*)&W[(size_t)(o0 + t) * K_DIM + k0 + kq];
            Ws[kq + 0][t] = wv.x; Ws[kq + 1][t] = wv.y;
            Ws[kq + 2][t] = wv.z; Ws[kq + 3][t] = wv.w;
        }
        __syncthreads();
#pragma unroll
        for (int k = 0; k < 16; k++) {
            float a[4], w[4];
#pragma unroll
            for (int i = 0; i < 4; i++) a[i] = As[k][tm + i];
#pragma unroll
            for (int j = 0; j < 4; j++) w[j] = Ws[k][tn + j];
#pragma unroll
            for (int i = 0; i < 4; i++)
#pragma unroll
                for (int j = 0; j < 4; j++) Pacc[i][j] = fmaf(a[i], w[j], Pacc[i][j]);
        }
        __syncthreads();
    }
#pragma unroll
    for (int i = 0; i < 4; i++)
#pragma unroll
        for (int j = 0; j < 4; j++)
            curbuf[tm + i][tn + j] =
                __fadd_rn(__fadd_rn(Csum[i][j], Pacc[i][j]), bias[o0 + tn + j]);
    __syncthreads();
    if (tid < 64) {
        float mem = 0.0f;
#pragma unroll
        for (int t = 0; t < T_STEPS; t++) {
            mem = __fadd_rn(__fmul_rn(mem, DECAY_F32), curbuf[t][tid]);
            const float d = __fsub_rn(mem, 1.0f);
            const bool spk = d > 0.0f;
            out[(size_t)t * NCHAIN + (size_t)b0 * N_DIM + o0 + tid] = spk ? 1.0f : 0.0f;
            if (spk) mem = __fsub_rn(mem, 1.0f);
        }
    }
}

extern "C" void kernel_launch(void* const* d_in, const int* in_sizes, int n_in,
                              void* d_out, int out_size, void* d_ws, size_t ws_size,
                              hipStream_t stream) {
    const float* x = nullptr; const float* W = nullptr; const float* bias = nullptr;
    for (int i = 0; i < n_in; i++) {
        if      (in_sizes[i] == M_DIM * K_DIM) x    = (const float*)d_in[i];
        else if (in_sizes[i] == N_DIM * K_DIM) W    = (const float*)d_in[i];
        else if (in_sizes[i] == N_DIM)         bias = (const float*)d_in[i];
    }
    if (!x)    x    = (const float*)d_in[0];
    if (!W)    W    = (const float*)d_in[1];
    if (!bias) bias = (const float*)d_in[2];
    float* out = (float*)d_out;

    // workspace layout: counters + worklist + Wh + Wl
    const size_t off_cnt = 0;                                   // 128 u32
    const size_t off_wl  = 512;                                 // 128*2048 u32
    const size_t off_Wh  = off_wl + (size_t)128 * 2048 * 4;     // 1049088
    const size_t szW     = (size_t)N_DIM * K_DIM * 2;           // 8 MiB
    const size_t off_Wl  = off_Wh + szW;
    const size_t need    = off_Wl + szW;                        // ~17.8 MB

    if (ws_size < need) {
        dim3 grid(N_DIM / 64, BATCH);
        lif_openblas_q320<<<grid, 256, 0, stream>>>(x, W, bias, out);
        return;
    }

    char* ws = (char*)d_ws;
    unsigned int* counters = (unsigned int*)(ws + off_cnt);
    unsigned int* worklist = (unsigned int*)(ws + off_wl);
    u16* Wh = (u16*)(ws + off_Wh);
    u16* Wl = (u16*)(ws + off_Wl);

    wsplit<<<(N_DIM * K_DIM / 8) / 256, 256, 0, stream>>>(W, Wh, Wl, counters);
    dim3 ggrid(N_DIM / 128, M_DIM / 256);   // (16, 32) -> 512 tiles
    gemm_lif<<<ggrid, 512, 132096, stream>>>(x, Wh, Wl, bias, out, counters, worklist);
    lif_repair2<<<128 * RJ, 256, 0, stream>>>(x, W, bias, counters, worklist, out);
}

// Round 16
// 416.860 us; speedup vs baseline: 1.3845x; 1.3583x over previous
//
#include <hip/hip_runtime.h>
#include <hip/hip_bf16.h>
#include <math.h>

// ---------------------------------------------------------------------------
// LIF layer, round 26 = exact revert to R22 (best measured: wall 418.5us,
// absmax 0.0; gemm 239.5us benched consistently in R20/R21/R22).
//
// R24/R25 post-mortem: BOTH pre-split-W variants (gload_lds 3-ring, and
// reg-load u16 2-ring with the identical R22 loop) regressed ~150us with
// the same signature (MfmaUtil 37->21-23, VALU 30->15, FETCH flat, gemm
// WRITE +20MB). R25 refutes R24's code-footprint theory (same loop, same
// VGPR). Common factor: B reads of freshly-written workspace Wh/Wl —
// dirty-L2 interaction we cannot fix blind. Idea abandoned; locking in the
// known-good R22 configuration.
//
// Pipeline: memset(counters) / gemm_lif (fused Dekker split + bf16x3 MFMA
// GEMM + in-LDS LIF scan) / lif_repair2. Fallback: R8 exact kernel.
// ---------------------------------------------------------------------------

typedef unsigned short u16;
typedef __attribute__((ext_vector_type(8))) short bf16x8;
typedef __attribute__((ext_vector_type(4))) float f32x4;

constexpr int T_STEPS = 64;
constexpr int BATCH   = 128;
constexpr int K_DIM   = 2048;
constexpr int N_DIM   = 2048;
constexpr int M_DIM   = T_STEPS * BATCH;      // 8192
constexpr int NCHAIN  = BATCH * N_DIM;        // 262144

constexpr float DECAY_F32 = (float)0.6065306597126334;
constexpr float BAND      = 2e-4f;            // error tail ~6e-5, 3.3x margin

// ---------------------------------------------------------------------------
// k3: fused split+GEMM+scan. bf16x3 (hh+hl+lh), tile = (64t x 4b) x 128o,
// 8 waves, BK=32, 2-slot LDS ring (96 KiB), XCD swizzle, counted vmcnt.
// Epilogue: in-LDS LIF scan, spikes -> out, flagged chains -> worklist.
// ---------------------------------------------------------------------------
__global__ __launch_bounds__(512, 2)
void gemm_lif(const float* __restrict__ X, const float* __restrict__ W,
              const float* __restrict__ bias, float* __restrict__ out,
              unsigned int* __restrict__ counters,
              unsigned int* __restrict__ worklist) {
    extern __shared__ __align__(16) u16 smem[];
    u16* const sAh = smem;                          // [2][8192]
    u16* const sAl = smem + 2 * 8192;               // [2][8192]
    u16* const sBh = smem + 4 * 8192;               // [2][4096]
    u16* const sBl = smem + 4 * 8192 + 2 * 4096;    // [2][4096]

    const int tid  = threadIdx.x;
    const int orig = blockIdx.x + gridDim.x * blockIdx.y;   // 0..511
    // XCD-chunked swizzle (bijective: 512 % 8 == 0)
    const int wg   = (orig & 7) * 64 + (orig >> 3);
    const int b0i  = (wg >> 4) * 4;     // batch base (4 b per tile)
    const int n0   = (wg & 15) * 128;   // output-channel base
    const int lane = tid & 63;
    const int wave = tid >> 6;     // 0..7
    const int wm   = wave >> 1;    // 0..3 (64-row slab)
    const int wn   = wave & 1;     // 0..1 (64-col slab)

    // staging entry: tile row re = (tid>>6)*16 + (tid&15), k-slot ((tid>>4)&3)*8
    // tile row r <-> global A row (r>>2)*128 + b0i + (r&3)   [t = r>>2, bl = r&3]
    const int re   = (tid >> 6) * 16 + (tid & 15);   // 0..127
    const int ks_e = ((tid >> 4) & 3) * 8;
    const size_t a0f = (size_t)((re >> 2) * 128 + b0i + (re & 3)) * K_DIM + ks_e;
    const size_t a1f = (size_t)(((re >> 2) + 32) * 128 + b0i + (re & 3)) * K_DIM + ks_e;
    const size_t b0f = (size_t)(n0 + re) * K_DIM + ks_e;
    const int wA0 = tid * 8;            // u16 offset within a slot
    const int wA1 = 4096 + tid * 8;
    const int wB0 = tid * 8;

    f32x4 acc[4][4];
#pragma unroll
    for (int i = 0; i < 4; i++)
#pragma unroll
        for (int j = 0; j < 4; j++) acc[i][j] = (f32x4){0.f, 0.f, 0.f, 0.f};

    float4 g0[6], g1[6];

#define GLOAD(SET, kc) do {                                                  \
        const size_t k_ = (size_t)(kc) * 32;                                 \
        g##SET[0] = *(const float4*)(X + a0f + k_);                          \
        g##SET[1] = *(const float4*)(X + a0f + k_ + 4);                      \
        g##SET[2] = *(const float4*)(X + a1f + k_);                          \
        g##SET[3] = *(const float4*)(X + a1f + k_ + 4);                      \
        g##SET[4] = *(const float4*)(W + b0f + k_);                          \
        g##SET[5] = *(const float4*)(W + b0f + k_ + 4);                      \
    } while (0)

#define DEK8(v0, v1, HI, LO) do {                                            \
        const float f_[8] = {v0.x, v0.y, v0.z, v0.w, v1.x, v1.y, v1.z, v1.w};\
        unsigned int hp_[4], lp_[4];                                         \
        _Pragma("unroll")                                                    \
        for (int q_ = 0; q_ < 8; q_ += 2) {                                  \
            u16 hh_[2], ll_[2];                                              \
            _Pragma("unroll")                                                \
            for (int e_ = 0; e_ < 2; e_++) {                                 \
                __hip_bfloat16 hb_ = __float2bfloat16(f_[q_ + e_]);          \
                const float hf_ = __bfloat162float(hb_);                     \
                __hip_bfloat16 lb_ = __float2bfloat16(f_[q_ + e_] - hf_);    \
                hh_[e_] = *(u16*)&hb_;                                       \
                ll_[e_] = *(u16*)&lb_;                                       \
            }                                                                \
            hp_[q_ >> 1] = (unsigned int)hh_[0] | ((unsigned int)hh_[1] << 16); \
            lp_[q_ >> 1] = (unsigned int)ll_[0] | ((unsigned int)ll_[1] << 16); \
        }                                                                    \
        HI = make_uint4(hp_[0], hp_[1], hp_[2], hp_[3]);                     \
        LO = make_uint4(lp_[0], lp_[1], lp_[2], lp_[3]);                     \
    } while (0)

#define CONVWRITE(s, SET) do {                                               \
        uint4 hA0_, lA0_, hA1_, lA1_, hB_, lB_;                              \
        DEK8(g##SET[0], g##SET[1], hA0_, lA0_);                              \
        DEK8(g##SET[2], g##SET[3], hA1_, lA1_);                              \
        DEK8(g##SET[4], g##SET[5], hB_, lB_);                                \
        *(uint4*)&sAh[(s) * 8192 + wA0] = hA0_;                              \
        *(uint4*)&sAl[(s) * 8192 + wA0] = lA0_;                              \
        *(uint4*)&sAh[(s) * 8192 + wA1] = hA1_;                              \
        *(uint4*)&sAl[(s) * 8192 + wA1] = lA1_;                              \
        *(uint4*)&sBh[(s) * 4096 + wB0] = hB_;                               \
        *(uint4*)&sBl[(s) * 4096 + wB0] = lB_;                               \
    } while (0)

#define COMPUTE(rs) do {                                                     \
        bf16x8 fah[4], fal[4], fbh[4], fbl[4];                               \
        _Pragma("unroll")                                                    \
        for (int ti = 0; ti < 4; ti++) {                                     \
            const int ta = wm * 4 + ti;                                      \
            fah[ti] = *(const bf16x8*)&sAh[(rs) * 8192 + (ta * 64 + lane) * 8]; \
            fal[ti] = *(const bf16x8*)&sAl[(rs) * 8192 + (ta * 64 + lane) * 8]; \
        }                                                                    \
        _Pragma("unroll")                                                    \
        for (int tj = 0; tj < 4; tj++) {                                     \
            const int tb = wn * 4 + tj;                                      \
            fbh[tj] = *(const bf16x8*)&sBh[(rs) * 4096 + (tb * 64 + lane) * 8]; \
            fbl[tj] = *(const bf16x8*)&sBl[(rs) * 4096 + (tb * 64 + lane) * 8]; \
        }                                                                    \
        __builtin_amdgcn_s_setprio(1);                                       \
        _Pragma("unroll")                                                    \
        for (int ti = 0; ti < 4; ti++)                                       \
        _Pragma("unroll")                                                    \
        for (int tj = 0; tj < 4; tj++) {                                     \
            acc[ti][tj] = __builtin_amdgcn_mfma_f32_16x16x32_bf16(           \
                fah[ti], fbh[tj], acc[ti][tj], 0, 0, 0);                     \
            acc[ti][tj] = __builtin_amdgcn_mfma_f32_16x16x32_bf16(           \
                fah[ti], fbl[tj], acc[ti][tj], 0, 0, 0);                     \
            acc[ti][tj] = __builtin_amdgcn_mfma_f32_16x16x32_bf16(           \
                fal[ti], fbh[tj], acc[ti][tj], 0, 0, 0);                     \
        }                                                                    \
        __builtin_amdgcn_s_setprio(0);                                       \
    } while (0)

#define BAR do {                                                             \
        __builtin_amdgcn_sched_barrier(0);                                   \
        __builtin_amdgcn_s_barrier();                                        \
        __builtin_amdgcn_sched_barrier(0);                                   \
    } while (0)
#define VMW(n) do {                                                          \
        asm volatile("s_waitcnt vmcnt(" #n ")" ::: "memory");                \
        __builtin_amdgcn_sched_barrier(0);                                   \
    } while (0)
#define LGKM0 do {                                                           \
        asm volatile("s_waitcnt lgkmcnt(0)" ::: "memory");                   \
        __builtin_amdgcn_sched_barrier(0);                                   \
    } while (0)

    // prologue: G(0) -> slot 0; G(1) in flight
    GLOAD(0, 0);
    VMW(0);
    CONVWRITE(0, 0);
    GLOAD(1, 1);
    LGKM0;

    // main loop: even/odd bodies, GLOADs reach kc+2 = 61
    for (int kc = 0; kc < 60; kc += 2) {
        // even body kc: read slot 0, write slot 1 from g1, load g0 <- kc+2
        BAR;
        GLOAD(0, kc + 2);
        VMW(6);
        CONVWRITE(1, 1);
        LGKM0;
        COMPUTE(0);
        // odd body kc+1: read slot 1, write slot 0 from g0, load g1 <- kc+3
        BAR;
        GLOAD(1, kc + 3);
        VMW(6);
        CONVWRITE(0, 0);
        LGKM0;
        COMPUTE(1);
    }
    // kc = 60 (even, full): GLOAD(0, 62)
    BAR;
    GLOAD(0, 62);
    VMW(6);
    CONVWRITE(1, 1);
    LGKM0;
    COMPUTE(0);
    // kc = 61 (odd, full): GLOAD(1, 63)
    BAR;
    GLOAD(1, 63);
    VMW(6);
    CONVWRITE(0, 0);
    LGKM0;
    COMPUTE(1);
    // kc = 62: no more loads; drain G(63), write slot 1 from g1
    BAR;
    VMW(0);
    CONVWRITE(1, 1);
    LGKM0;
    COMPUTE(0);
    // kc = 63: read slot 1 only
    BAR;
    COMPUTE(1);

#undef LGKM0
#undef VMW
#undef BAR
#undef COMPUTE
#undef CONVWRITE
#undef DEK8
#undef GLOAD

    // ------------------------------------------------------------------
    // epilogue: reuse smem as cur[256][129] f32 (132096 B), in-LDS scan.
    // ------------------------------------------------------------------
    __syncthreads();                    // all ring reads done, smem reusable
    float* const curL = (float*)smem;

#pragma unroll
    for (int tj = 0; tj < 4; tj++) {
        const int col = wn * 64 + tj * 16 + (lane & 15);
        const float bv = bias[n0 + col];
#pragma unroll
        for (int ti = 0; ti < 4; ti++) {
            const int rb = wm * 64 + ti * 16 + (lane >> 4) * 4;
#pragma unroll
            for (int r = 0; r < 4; r++)
                curL[(rb + r) * 129 + col] = acc[ti][tj][r] + bv;
        }
    }
    __syncthreads();                    // cur tile complete

    // scan: 512 threads = 512 chains (bl = tid>>7, col = tid&127)
    {
        const int bl  = tid >> 7;
        const int col = tid & 127;
        const int b   = b0i + bl;
        const int o   = n0 + col;
        float mem = 0.0f;
        bool flag = false;
#pragma unroll
        for (int t = 0; t < T_STEPS; t++) {
            const float cv = curL[(t * 4 + bl) * 129 + col];
            mem = __fadd_rn(__fmul_rn(mem, DECAY_F32), cv);
            const float d = __fsub_rn(mem, 1.0f);
            const bool spk = d > 0.0f;
            if (fabsf(d) < BAND) flag = true;
            out[(size_t)t * NCHAIN + (size_t)b * N_DIM + o] = spk ? 1.0f : 0.0f;
            if (spk) mem = __fsub_rn(mem, 1.0f);
        }
        if (flag) {
            const unsigned int p = atomicAdd(&counters[b], 1u);
            worklist[b * 2048 + p] = (unsigned int)o;
        }
    }
}

// ---------------------------------------------------------------------------
// k5: b-grouped exact repair + register-staged chunk double-buffer (R21).
// ---------------------------------------------------------------------------
#define RG 16    // chains per group
#define RJ 4     // block-strides per b
#define BKR 64   // k-chunk (320 = 5*64: panel boundaries land on chunk edges)

__global__ __launch_bounds__(256)
void lif_repair2(const float* __restrict__ X, const float* __restrict__ W,
                 const float* __restrict__ bias,
                 const unsigned int* __restrict__ counters,
                 const unsigned int* __restrict__ worklist,
                 float* __restrict__ out) {
    __shared__ float sX[BKR][T_STEPS + 1];      // [k][t] 16.25 KiB
    __shared__ float sW[RG][BKR + 1];           // [o][k]  4.06 KiB
    __shared__ float scur[T_STEPS][RG + 1];
    __shared__ float sspk[T_STEPS][RG + 1];
    __shared__ int   so[RG];

    const int b = blockIdx.x / RJ;
    const int j = blockIdx.x % RJ;
    const unsigned int n_b = counters[b];
    if (n_b == 0) return;
    const int ngroups = (int)(n_b + RG - 1) / RG;

    const int tid = threadIdx.x;
    const int t   = tid & 63;
    const int oi  = tid >> 6;          // 0..3, owns o-slots 4*oi .. 4*oi+3

    const int ts  = tid >> 2;          // X row 0..63
    const int kq  = (tid & 3) * 16;    // X col quarter
    const int wo  = tid >> 4;          // W row 0..15
    const int wkq = (tid & 15) * 4;    // W col quad

    for (int g = j; g < ngroups; g += RJ) {
        if (tid < RG) {
            const int slot = g * RG + tid;
            so[tid] = (slot < (int)n_b) ? (int)worklist[b * 2048 + slot] : -1;
        }
        __syncthreads();

        float Csum[4] = {0.f, 0.f, 0.f, 0.f};
        float P[4]    = {0.f, 0.f, 0.f, 0.f};

        // preload chunk 0 into registers
        float4 rx[4];
        float4 rw;
        {
            const float* srcx = &X[(size_t)(ts * BATCH + b) * K_DIM + kq];
#pragma unroll
            for (int q = 0; q < 4; q++) rx[q] = *(const float4*)(srcx + q * 4);
            const int o = so[wo];
            rw = (o >= 0) ? *(const float4*)&W[(size_t)o * K_DIM + wkq]
                          : make_float4(0.f, 0.f, 0.f, 0.f);
        }

        for (int c = 0; c < K_DIM / BKR; c++) {
            if (c > 0 && (c % 5) == 0) {       // k = 320*j panel boundary
#pragma unroll
                for (int q = 0; q < 4; q++) {
                    Csum[q] = __fadd_rn(Csum[q], P[q]);
                    P[q] = 0.f;
                }
            }
            __syncthreads();                   // prev chunk's LDS reads done
            // write staged registers to LDS (same values/layout as R20)
#pragma unroll
            for (int q = 0; q < 4; q++) {
                sX[kq + q * 4 + 0][ts] = rx[q].x;
                sX[kq + q * 4 + 1][ts] = rx[q].y;
                sX[kq + q * 4 + 2][ts] = rx[q].z;
                sX[kq + q * 4 + 3][ts] = rx[q].w;
            }
            sW[wo][wkq + 0] = rw.x; sW[wo][wkq + 1] = rw.y;
            sW[wo][wkq + 2] = rw.z; sW[wo][wkq + 3] = rw.w;
            // issue next chunk's global loads (hide under compute below)
            if (c + 1 < K_DIM / BKR) {
                const int k1 = (c + 1) * BKR;
                const float* srcx = &X[(size_t)(ts * BATCH + b) * K_DIM + k1 + kq];
#pragma unroll
                for (int q = 0; q < 4; q++) rx[q] = *(const float4*)(srcx + q * 4);
                const int o = so[wo];
                rw = (o >= 0) ? *(const float4*)&W[(size_t)o * K_DIM + k1 + wkq]
                              : make_float4(0.f, 0.f, 0.f, 0.f);
            }
            __syncthreads();                   // LDS chunk c ready
            // exact sequential-k FMA, 4 independent chains (ILP)
#pragma unroll 8
            for (int k = 0; k < BKR; k++) {
                const float xv = sX[k][t];
#pragma unroll
                for (int q = 0; q < 4; q++)
                    P[q] = fmaf(xv, sW[oi * 4 + q][k], P[q]);
            }
        }
        __syncthreads();
#pragma unroll
        for (int q = 0; q < 4; q++) {
            Csum[q] = __fadd_rn(Csum[q], P[q]);    // final 128-elem panel
            const int o = so[oi * 4 + q];
            scur[t][oi * 4 + q] = (o >= 0) ? __fadd_rn(Csum[q], bias[o]) : 0.f;
        }
        __syncthreads();
        if (tid < RG && so[tid] >= 0) {
            float mem = 0.0f;
            for (int tt = 0; tt < T_STEPS; tt++) {
                mem = __fadd_rn(__fmul_rn(mem, DECAY_F32), scur[tt][tid]);
                const float d = __fsub_rn(mem, 1.0f);
                const bool spk = d > 0.0f;
                sspk[tt][tid] = spk ? 1.0f : 0.0f;
                if (spk) mem = __fsub_rn(mem, 1.0f);
            }
        }
        __syncthreads();
#pragma unroll
        for (int q = 0; q < 4; q++) {
            const int o = so[oi * 4 + q];
            if (o >= 0)
                out[(size_t)t * NCHAIN + (size_t)b * N_DIM + o] = sspk[t][oi * 4 + q];
        }
        __syncthreads();
    }
}

// ---------------------------------------------------------------------------
// FALLBACK (R8, known-passing, ws-free).
// ---------------------------------------------------------------------------
__global__ __launch_bounds__(256)
void lif_openblas_q320(const float* __restrict__ X, const float* __restrict__ W,
                       const float* __restrict__ bias, float* __restrict__ out) {
    __shared__ float As[16][T_STEPS + 4];
    __shared__ float Ws[16][64 + 4];
    __shared__ float curbuf[T_STEPS][64 + 1];
    const int tid = threadIdx.x;
    const int o0 = blockIdx.x * 64, b0 = blockIdx.y;
    const int tm = (tid & 15) * 4, tn = (tid >> 4) * 4;
    float Csum[4][4], Pacc[4][4];
#pragma unroll
    for (int i = 0; i < 4; i++)
#pragma unroll
        for (int j = 0; j < 4; j++) { Csum[i][j] = 0.f; Pacc[i][j] = 0.f; }
    for (int c = 0; c < K_DIM / 16; c++) {
        if (c > 0 && (c % 20) == 0) {
#pragma unroll
            for (int i = 0; i < 4; i++)
#pragma unroll
                for (int j = 0; j < 4; j++) {
                    Csum[i][j] = __fadd_rn(Csum[i][j], Pacc[i][j]);
                    Pacc[i][j] = 0.f;
                }
        }
        const int k0 = c * 16;
        {
            const int t = tid >> 2, kq = (tid & 3) * 4;
            const float4 av = *(const float4*)&X[(size_t)(t * BATCH + b0) * K_DIM + k0 + kq];
            As[kq + 0][t] = av.x; As[kq + 1][t] = av.y;
            As[kq + 2][t] = av.z; As[kq + 3][t] = av.w;
            const float4 wv = *(const float4*)&W[(size_t)(o0 + t) * K_DIM + k0 + kq];
            Ws[kq + 0][t] = wv.x; Ws[kq + 1][t] = wv.y;
            Ws[kq + 2][t] = wv.z; Ws[kq + 3][t] = wv.w;
        }
        __syncthreads();
#pragma unroll
        for (int k = 0; k < 16; k++) {
            float a[4], w[4];
#pragma unroll
            for (int i = 0; i < 4; i++) a[i] = As[k][tm + i];
#pragma unroll
            for (int j = 0; j < 4; j++) w[j] = Ws[k][tn + j];
#pragma unroll
            for (int i = 0; i < 4; i++)
#pragma unroll
                for (int j = 0; j < 4; j++) Pacc[i][j] = fmaf(a[i], w[j], Pacc[i][j]);
        }
        __syncthreads();
    }
#pragma unroll
    for (int i = 0; i < 4; i++)
#pragma unroll
        for (int j = 0; j < 4; j++)
            curbuf[tm + i][tn + j] =
                __fadd_rn(__fadd_rn(Csum[i][j], Pacc[i][j]), bias[o0 + tn + j]);
    __syncthreads();
    if (tid < 64) {
        float mem = 0.0f;
#pragma unroll
        for (int t = 0; t < T_STEPS; t++) {
            mem = __fadd_rn(__fmul_rn(mem, DECAY_F32), curbuf[t][tid]);
            const float d = __fsub_rn(mem, 1.0f);
            const bool spk = d > 0.0f;
            out[(size_t)t * NCHAIN + (size_t)b0 * N_DIM + o0 + tid] = spk ? 1.0f : 0.0f;
            if (spk) mem = __fsub_rn(mem, 1.0f);
        }
    }
}

extern "C" void kernel_launch(void* const* d_in, const int* in_sizes, int n_in,
                              void* d_out, int out_size, void* d_ws, size_t ws_size,
                              hipStream_t stream) {
    const float* x = nullptr; const float* W = nullptr; const float* bias = nullptr;
    for (int i = 0; i < n_in; i++) {
        if      (in_sizes[i] == M_DIM * K_DIM) x    = (const float*)d_in[i];
        else if (in_sizes[i] == N_DIM * K_DIM) W    = (const float*)d_in[i];
        else if (in_sizes[i] == N_DIM)         bias = (const float*)d_in[i];
    }
    if (!x)    x    = (const float*)d_in[0];
    if (!W)    W    = (const float*)d_in[1];
    if (!bias) bias = (const float*)d_in[2];
    float* out = (float*)d_out;

    // workspace layout: counters + worklist only
    const size_t off_cnt = 0;                                   // 128 u32
    const size_t off_wl  = 512;                                 // 128*2048 u32
    const size_t need    = off_wl + (size_t)128 * 2048 * 4;     // ~1.05 MB

    if (ws_size < need) {
        dim3 grid(N_DIM / 64, BATCH);
        lif_openblas_q320<<<grid, 256, 0, stream>>>(x, W, bias, out);
        return;
    }

    char* ws = (char*)d_ws;
    unsigned int* counters = (unsigned int*)(ws + off_cnt);
    unsigned int* worklist = (unsigned int*)(ws + off_wl);

    hipMemsetAsync(counters, 0, 512, stream);   // graph-capturable

    dim3 ggrid(N_DIM / 128, M_DIM / 256);   // (16, 32) -> 512 tiles
    gemm_lif<<<ggrid, 512, 132096, stream>>>(x, W, bias, out, counters, worklist);
    lif_repair2<<<128 * RJ, 256, 0, stream>>>(x, W, bias, counters, worklist, out);
}

// Round 17
// 412.839 us; speedup vs baseline: 1.3980x; 1.0097x over previous
//
#include <hip/hip_runtime.h>
#include <hip/hip_bf16.h>
#include <math.h>

// ---------------------------------------------------------------------------
// LIF layer, round 27: R26/R22 pipeline with ONE reorder — the per-step
// lgkmcnt(0) moves from before COMPUTE to after it. The wait exists only to
// publish this wave's 6 ds_writes at the NEXT s_barrier; COMPUTE reads the
// OTHER slot (published last step). Moving it lets the ds_write drain retire
// under the 48-MFMA cluster instead of serializing (~150-200 cy/step).
// Invariant "slot writes drained before the barrier that publishes it" is
// preserved bit-for-bit; no address/order/MFMA change -> C bitwise identical
// -> absmax 0.0.
//
// R26 post-mortem: revert confirmed best-known (wall 416.9, gemm 240,
// MfmaUtil 37.5). Pre-split-W family abandoned (2x -150us, R24/R25).
//
// Pipeline: memset(counters) / gemm_lif (fused Dekker split + bf16x3 MFMA
// GEMM + in-LDS LIF scan) / lif_repair2. Fallback: R8 exact kernel.
// ---------------------------------------------------------------------------

typedef unsigned short u16;
typedef __attribute__((ext_vector_type(8))) short bf16x8;
typedef __attribute__((ext_vector_type(4))) float f32x4;

constexpr int T_STEPS = 64;
constexpr int BATCH   = 128;
constexpr int K_DIM   = 2048;
constexpr int N_DIM   = 2048;
constexpr int M_DIM   = T_STEPS * BATCH;      // 8192
constexpr int NCHAIN  = BATCH * N_DIM;        // 262144

constexpr float DECAY_F32 = (float)0.6065306597126334;
constexpr float BAND      = 2e-4f;            // error tail ~6e-5, 3.3x margin

// ---------------------------------------------------------------------------
// k3: fused split+GEMM+scan. bf16x3 (hh+hl+lh), tile = (64t x 4b) x 128o,
// 8 waves, BK=32, 2-slot LDS ring (96 KiB), XCD swizzle, counted vmcnt.
// Epilogue: in-LDS LIF scan, spikes -> out, flagged chains -> worklist.
// ---------------------------------------------------------------------------
__global__ __launch_bounds__(512, 2)
void gemm_lif(const float* __restrict__ X, const float* __restrict__ W,
              const float* __restrict__ bias, float* __restrict__ out,
              unsigned int* __restrict__ counters,
              unsigned int* __restrict__ worklist) {
    extern __shared__ __align__(16) u16 smem[];
    u16* const sAh = smem;                          // [2][8192]
    u16* const sAl = smem + 2 * 8192;               // [2][8192]
    u16* const sBh = smem + 4 * 8192;               // [2][4096]
    u16* const sBl = smem + 4 * 8192 + 2 * 4096;    // [2][4096]

    const int tid  = threadIdx.x;
    const int orig = blockIdx.x + gridDim.x * blockIdx.y;   // 0..511
    // XCD-chunked swizzle (bijective: 512 % 8 == 0)
    const int wg   = (orig & 7) * 64 + (orig >> 3);
    const int b0i  = (wg >> 4) * 4;     // batch base (4 b per tile)
    const int n0   = (wg & 15) * 128;   // output-channel base
    const int lane = tid & 63;
    const int wave = tid >> 6;     // 0..7
    const int wm   = wave >> 1;    // 0..3 (64-row slab)
    const int wn   = wave & 1;     // 0..1 (64-col slab)

    // staging entry: tile row re = (tid>>6)*16 + (tid&15), k-slot ((tid>>4)&3)*8
    // tile row r <-> global A row (r>>2)*128 + b0i + (r&3)   [t = r>>2, bl = r&3]
    const int re   = (tid >> 6) * 16 + (tid & 15);   // 0..127
    const int ks_e = ((tid >> 4) & 3) * 8;
    const size_t a0f = (size_t)((re >> 2) * 128 + b0i + (re & 3)) * K_DIM + ks_e;
    const size_t a1f = (size_t)(((re >> 2) + 32) * 128 + b0i + (re & 3)) * K_DIM + ks_e;
    const size_t b0f = (size_t)(n0 + re) * K_DIM + ks_e;
    const int wA0 = tid * 8;            // u16 offset within a slot
    const int wA1 = 4096 + tid * 8;
    const int wB0 = tid * 8;

    f32x4 acc[4][4];
#pragma unroll
    for (int i = 0; i < 4; i++)
#pragma unroll
        for (int j = 0; j < 4; j++) acc[i][j] = (f32x4){0.f, 0.f, 0.f, 0.f};

    float4 g0[6], g1[6];

#define GLOAD(SET, kc) do {                                                  \
        const size_t k_ = (size_t)(kc) * 32;                                 \
        g##SET[0] = *(const float4*)(X + a0f + k_);                          \
        g##SET[1] = *(const float4*)(X + a0f + k_ + 4);                      \
        g##SET[2] = *(const float4*)(X + a1f + k_);                          \
        g##SET[3] = *(const float4*)(X + a1f + k_ + 4);                      \
        g##SET[4] = *(const float4*)(W + b0f + k_);                          \
        g##SET[5] = *(const float4*)(W + b0f + k_ + 4);                      \
    } while (0)

#define DEK8(v0, v1, HI, LO) do {                                            \
        const float f_[8] = {v0.x, v0.y, v0.z, v0.w, v1.x, v1.y, v1.z, v1.w};\
        unsigned int hp_[4], lp_[4];                                         \
        _Pragma("unroll")                                                    \
        for (int q_ = 0; q_ < 8; q_ += 2) {                                  \
            u16 hh_[2], ll_[2];                                              \
            _Pragma("unroll")                                                \
            for (int e_ = 0; e_ < 2; e_++) {                                 \
                __hip_bfloat16 hb_ = __float2bfloat16(f_[q_ + e_]);          \
                const float hf_ = __bfloat162float(hb_);                     \
                __hip_bfloat16 lb_ = __float2bfloat16(f_[q_ + e_] - hf_);    \
                hh_[e_] = *(u16*)&hb_;                                       \
                ll_[e_] = *(u16*)&lb_;                                       \
            }                                                                \
            hp_[q_ >> 1] = (unsigned int)hh_[0] | ((unsigned int)hh_[1] << 16); \
            lp_[q_ >> 1] = (unsigned int)ll_[0] | ((unsigned int)ll_[1] << 16); \
        }                                                                    \
        HI = make_uint4(hp_[0], hp_[1], hp_[2], hp_[3]);                     \
        LO = make_uint4(lp_[0], lp_[1], lp_[2], lp_[3]);                     \
    } while (0)

#define CONVWRITE(s, SET) do {                                               \
        uint4 hA0_, lA0_, hA1_, lA1_, hB_, lB_;                              \
        DEK8(g##SET[0], g##SET[1], hA0_, lA0_);                              \
        DEK8(g##SET[2], g##SET[3], hA1_, lA1_);                              \
        DEK8(g##SET[4], g##SET[5], hB_, lB_);                                \
        *(uint4*)&sAh[(s) * 8192 + wA0] = hA0_;                              \
        *(uint4*)&sAl[(s) * 8192 + wA0] = lA0_;                              \
        *(uint4*)&sAh[(s) * 8192 + wA1] = hA1_;                              \
        *(uint4*)&sAl[(s) * 8192 + wA1] = lA1_;                              \
        *(uint4*)&sBh[(s) * 4096 + wB0] = hB_;                               \
        *(uint4*)&sBl[(s) * 4096 + wB0] = lB_;                               \
    } while (0)

#define COMPUTE(rs) do {                                                     \
        bf16x8 fah[4], fal[4], fbh[4], fbl[4];                               \
        _Pragma("unroll")                                                    \
        for (int ti = 0; ti < 4; ti++) {                                     \
            const int ta = wm * 4 + ti;                                      \
            fah[ti] = *(const bf16x8*)&sAh[(rs) * 8192 + (ta * 64 + lane) * 8]; \
            fal[ti] = *(const bf16x8*)&sAl[(rs) * 8192 + (ta * 64 + lane) * 8]; \
        }                                                                    \
        _Pragma("unroll")                                                    \
        for (int tj = 0; tj < 4; tj++) {                                     \
            const int tb = wn * 4 + tj;                                      \
            fbh[tj] = *(const bf16x8*)&sBh[(rs) * 4096 + (tb * 64 + lane) * 8]; \
            fbl[tj] = *(const bf16x8*)&sBl[(rs) * 4096 + (tb * 64 + lane) * 8]; \
        }                                                                    \
        __builtin_amdgcn_s_setprio(1);                                       \
        _Pragma("unroll")                                                    \
        for (int ti = 0; ti < 4; ti++)                                       \
        _Pragma("unroll")                                                    \
        for (int tj = 0; tj < 4; tj++) {                                     \
            acc[ti][tj] = __builtin_amdgcn_mfma_f32_16x16x32_bf16(           \
                fah[ti], fbh[tj], acc[ti][tj], 0, 0, 0);                     \
            acc[ti][tj] = __builtin_amdgcn_mfma_f32_16x16x32_bf16(           \
                fah[ti], fbl[tj], acc[ti][tj], 0, 0, 0);                     \
            acc[ti][tj] = __builtin_amdgcn_mfma_f32_16x16x32_bf16(           \
                fal[ti], fbh[tj], acc[ti][tj], 0, 0, 0);                     \
        }                                                                    \
        __builtin_amdgcn_s_setprio(0);                                       \
    } while (0)

#define BAR do {                                                             \
        __builtin_amdgcn_sched_barrier(0);                                   \
        __builtin_amdgcn_s_barrier();                                        \
        __builtin_amdgcn_sched_barrier(0);                                   \
    } while (0)
#define VMW(n) do {                                                          \
        asm volatile("s_waitcnt vmcnt(" #n ")" ::: "memory");                \
        __builtin_amdgcn_sched_barrier(0);                                   \
    } while (0)
#define LGKM0 do {                                                           \
        asm volatile("s_waitcnt lgkmcnt(0)" ::: "memory");                   \
        __builtin_amdgcn_sched_barrier(0);                                   \
    } while (0)

    // prologue: G(0) -> slot 0; G(1) in flight
    GLOAD(0, 0);
    VMW(0);
    CONVWRITE(0, 0);
    GLOAD(1, 1);
    LGKM0;                      // slot-0 writes published before first BAR

    // main loop: even/odd bodies, GLOADs reach kc+2 = 61.
    // LGKM0 now AFTER COMPUTE: ds_writes drain under the MFMA cluster,
    // still before the next BAR (publication invariant unchanged).
    for (int kc = 0; kc < 60; kc += 2) {
        // even body kc: read slot 0, write slot 1 from g1, load g0 <- kc+2
        BAR;
        GLOAD(0, kc + 2);
        VMW(6);
        CONVWRITE(1, 1);
        COMPUTE(0);
        LGKM0;
        // odd body kc+1: read slot 1, write slot 0 from g0, load g1 <- kc+3
        BAR;
        GLOAD(1, kc + 3);
        VMW(6);
        CONVWRITE(0, 0);
        COMPUTE(1);
        LGKM0;
    }
    // kc = 60 (even, full): GLOAD(0, 62)
    BAR;
    GLOAD(0, 62);
    VMW(6);
    CONVWRITE(1, 1);
    COMPUTE(0);
    LGKM0;
    // kc = 61 (odd, full): GLOAD(1, 63)
    BAR;
    GLOAD(1, 63);
    VMW(6);
    CONVWRITE(0, 0);
    COMPUTE(1);
    LGKM0;
    // kc = 62: no more loads; drain G(63), write slot 1 from g1
    BAR;
    VMW(0);
    CONVWRITE(1, 1);
    COMPUTE(0);
    LGKM0;
    // kc = 63: read slot 1 only
    BAR;
    COMPUTE(1);

#undef LGKM0
#undef VMW
#undef BAR
#undef COMPUTE
#undef CONVWRITE
#undef DEK8
#undef GLOAD

    // ------------------------------------------------------------------
    // epilogue: reuse smem as cur[256][129] f32 (132096 B), in-LDS scan.
    // ------------------------------------------------------------------
    __syncthreads();                    // all ring reads done, smem reusable
    float* const curL = (float*)smem;

#pragma unroll
    for (int tj = 0; tj < 4; tj++) {
        const int col = wn * 64 + tj * 16 + (lane & 15);
        const float bv = bias[n0 + col];
#pragma unroll
        for (int ti = 0; ti < 4; ti++) {
            const int rb = wm * 64 + ti * 16 + (lane >> 4) * 4;
#pragma unroll
            for (int r = 0; r < 4; r++)
                curL[(rb + r) * 129 + col] = acc[ti][tj][r] + bv;
        }
    }
    __syncthreads();                    // cur tile complete

    // scan: 512 threads = 512 chains (bl = tid>>7, col = tid&127)
    {
        const int bl  = tid >> 7;
        const int col = tid & 127;
        const int b   = b0i + bl;
        const int o   = n0 + col;
        float mem = 0.0f;
        bool flag = false;
#pragma unroll
        for (int t = 0; t < T_STEPS; t++) {
            const float cv = curL[(t * 4 + bl) * 129 + col];
            mem = __fadd_rn(__fmul_rn(mem, DECAY_F32), cv);
            const float d = __fsub_rn(mem, 1.0f);
            const bool spk = d > 0.0f;
            if (fabsf(d) < BAND) flag = true;
            out[(size_t)t * NCHAIN + (size_t)b * N_DIM + o] = spk ? 1.0f : 0.0f;
            if (spk) mem = __fsub_rn(mem, 1.0f);
        }
        if (flag) {
            const unsigned int p = atomicAdd(&counters[b], 1u);
            worklist[b * 2048 + p] = (unsigned int)o;
        }
    }
}

// ---------------------------------------------------------------------------
// k5: b-grouped exact repair + register-staged chunk double-buffer (R21).
// ---------------------------------------------------------------------------
#define RG 16    // chains per group
#define RJ 4     // block-strides per b
#define BKR 64   // k-chunk (320 = 5*64: panel boundaries land on chunk edges)

__global__ __launch_bounds__(256)
void lif_repair2(const float* __restrict__ X, const float* __restrict__ W,
                 const float* __restrict__ bias,
                 const unsigned int* __restrict__ counters,
                 const unsigned int* __restrict__ worklist,
                 float* __restrict__ out) {
    __shared__ float sX[BKR][T_STEPS + 1];      // [k][t] 16.25 KiB
    __shared__ float sW[RG][BKR + 1];           // [o][k]  4.06 KiB
    __shared__ float scur[T_STEPS][RG + 1];
    __shared__ float sspk[T_STEPS][RG + 1];
    __shared__ int   so[RG];

    const int b = blockIdx.x / RJ;
    const int j = blockIdx.x % RJ;
    const unsigned int n_b = counters[b];
    if (n_b == 0) return;
    const int ngroups = (int)(n_b + RG - 1) / RG;

    const int tid = threadIdx.x;
    const int t   = tid & 63;
    const int oi  = tid >> 6;          // 0..3, owns o-slots 4*oi .. 4*oi+3

    const int ts  = tid >> 2;          // X row 0..63
    const int kq  = (tid & 3) * 16;    // X col quarter
    const int wo  = tid >> 4;          // W row 0..15
    const int wkq = (tid & 15) * 4;    // W col quad

    for (int g = j; g < ngroups; g += RJ) {
        if (tid < RG) {
            const int slot = g * RG + tid;
            so[tid] = (slot < (int)n_b) ? (int)worklist[b * 2048 + slot] : -1;
        }
        __syncthreads();

        float Csum[4] = {0.f, 0.f, 0.f, 0.f};
        float P[4]    = {0.f, 0.f, 0.f, 0.f};

        // preload chunk 0 into registers
        float4 rx[4];
        float4 rw;
        {
            const float* srcx = &X[(size_t)(ts * BATCH + b) * K_DIM + kq];
#pragma unroll
            for (int q = 0; q < 4; q++) rx[q] = *(const float4*)(srcx + q * 4);
            const int o = so[wo];
            rw = (o >= 0) ? *(const float4*)&W[(size_t)o * K_DIM + wkq]
                          : make_float4(0.f, 0.f, 0.f, 0.f);
        }

        for (int c = 0; c < K_DIM / BKR; c++) {
            if (c > 0 && (c % 5) == 0) {       // k = 320*j panel boundary
#pragma unroll
                for (int q = 0; q < 4; q++) {
                    Csum[q] = __fadd_rn(Csum[q], P[q]);
                    P[q] = 0.f;
                }
            }
            __syncthreads();                   // prev chunk's LDS reads done
            // write staged registers to LDS (same values/layout as R20)
#pragma unroll
            for (int q = 0; q < 4; q++) {
                sX[kq + q * 4 + 0][ts] = rx[q].x;
                sX[kq + q * 4 + 1][ts] = rx[q].y;
                sX[kq + q * 4 + 2][ts] = rx[q].z;
                sX[kq + q * 4 + 3][ts] = rx[q].w;
            }
            sW[wo][wkq + 0] = rw.x; sW[wo][wkq + 1] = rw.y;
            sW[wo][wkq + 2] = rw.z; sW[wo][wkq + 3] = rw.w;
            // issue next chunk's global loads (hide under compute below)
            if (c + 1 < K_DIM / BKR) {
                const int k1 = (c + 1) * BKR;
                const float* srcx = &X[(size_t)(ts * BATCH + b) * K_DIM + k1 + kq];
#pragma unroll
                for (int q = 0; q < 4; q++) rx[q] = *(const float4*)(srcx + q * 4);
                const int o = so[wo];
                rw = (o >= 0) ? *(const float4*)&W[(size_t)o * K_DIM + k1 + wkq]
                              : make_float4(0.f, 0.f, 0.f, 0.f);
            }
            __syncthreads();                   // LDS chunk c ready
            // exact sequential-k FMA, 4 independent chains (ILP)
#pragma unroll 8
            for (int k = 0; k < BKR; k++) {
                const float xv = sX[k][t];
#pragma unroll
                for (int q = 0; q < 4; q++)
                    P[q] = fmaf(xv, sW[oi * 4 + q][k], P[q]);
            }
        }
        __syncthreads();
#pragma unroll
        for (int q = 0; q < 4; q++) {
            Csum[q] = __fadd_rn(Csum[q], P[q]);    // final 128-elem panel
            const int o = so[oi * 4 + q];
            scur[t][oi * 4 + q] = (o >= 0) ? __fadd_rn(Csum[q], bias[o]) : 0.f;
        }
        __syncthreads();
        if (tid < RG && so[tid] >= 0) {
            float mem = 0.0f;
            for (int tt = 0; tt < T_STEPS; tt++) {
                mem = __fadd_rn(__fmul_rn(mem, DECAY_F32), scur[tt][tid]);
                const float d = __fsub_rn(mem, 1.0f);
                const bool spk = d > 0.0f;
                sspk[tt][tid] = spk ? 1.0f : 0.0f;
                if (spk) mem = __fsub_rn(mem, 1.0f);
            }
        }
        __syncthreads();
#pragma unroll
        for (int q = 0; q < 4; q++) {
            const int o = so[oi * 4 + q];
            if (o >= 0)
                out[(size_t)t * NCHAIN + (size_t)b * N_DIM + o] = sspk[t][oi * 4 + q];
        }
        __syncthreads();
    }
}

// ---------------------------------------------------------------------------
// FALLBACK (R8, known-passing, ws-free).
// ---------------------------------------------------------------------------
__global__ __launch_bounds__(256)
void lif_openblas_q320(const float* __restrict__ X, const float* __restrict__ W,
                       const float* __restrict__ bias, float* __restrict__ out) {
    __shared__ float As[16][T_STEPS + 4];
    __shared__ float Ws[16][64 + 4];
    __shared__ float curbuf[T_STEPS][64 + 1];
    const int tid = threadIdx.x;
    const int o0 = blockIdx.x * 64, b0 = blockIdx.y;
    const int tm = (tid & 15) * 4, tn = (tid >> 4) * 4;
    float Csum[4][4], Pacc[4][4];
#pragma unroll
    for (int i = 0; i < 4; i++)
#pragma unroll
        for (int j = 0; j < 4; j++) { Csum[i][j] = 0.f; Pacc[i][j] = 0.f; }
    for (int c = 0; c < K_DIM / 16; c++) {
        if (c > 0 && (c % 20) == 0) {
#pragma unroll
            for (int i = 0; i < 4; i++)
#pragma unroll
                for (int j = 0; j < 4; j++) {
                    Csum[i][j] = __fadd_rn(Csum[i][j], Pacc[i][j]);
                    Pacc[i][j] = 0.f;
                }
        }
        const int k0 = c * 16;
        {
            const int t = tid >> 2, kq = (tid & 3) * 4;
            const float4 av = *(const float4*)&X[(size_t)(t * BATCH + b0) * K_DIM + k0 + kq];
            As[kq + 0][t] = av.x; As[kq + 1][t] = av.y;
            As[kq + 2][t] = av.z; As[kq + 3][t] = av.w;
            const float4 wv = *(const float4*)&W[(size_t)(o0 + t) * K_DIM + k0 + kq];
            Ws[kq + 0][t] = wv.x; Ws[kq + 1][t] = wv.y;
            Ws[kq + 2][t] = wv.z; Ws[kq + 3][t] = wv.w;
        }
        __syncthreads();
#pragma unroll
        for (int k = 0; k < 16; k++) {
            float a[4], w[4];
#pragma unroll
            for (int i = 0; i < 4; i++) a[i] = As[k][tm + i];
#pragma unroll
            for (int j = 0; j < 4; j++) w[j] = Ws[k][tn + j];
#pragma unroll
            for (int i = 0; i < 4; i++)
#pragma unroll
                for (int j = 0; j < 4; j++) Pacc[i][j] = fmaf(a[i], w[j], Pacc[i][j]);
        }
        __syncthreads();
    }
#pragma unroll
    for (int i = 0; i < 4; i++)
#pragma unroll
        for (int j = 0; j < 4; j++)
            curbuf[tm + i][tn + j] =
                __fadd_rn(__fadd_rn(Csum[i][j], Pacc[i][j]), bias[o0 + tn + j]);
    __syncthreads();
    if (tid < 64) {
        float mem = 0.0f;
#pragma unroll
        for (int t = 0; t < T_STEPS; t++) {
            mem = __fadd_rn(__fmul_rn(mem, DECAY_F32), curbuf[t][tid]);
            const float d = __fsub_rn(mem, 1.0f);
            const bool spk = d > 0.0f;
            out[(size_t)t * NCHAIN + (size_t)b0 * N_DIM + o0 + tid] = spk ? 1.0f : 0.0f;
            if (spk) mem = __fsub_rn(mem, 1.0f);
        }
    }
}

extern "C" void kernel_launch(void* const* d_in, const int* in_sizes, int n_in,
                              void* d_out, int out_size, void* d_ws, size_t ws_size,
                              hipStream_t stream) {
    const float* x = nullptr; const float* W = nullptr; const float* bias = nullptr;
    for (int i = 0; i < n_in; i++) {
        if      (in_sizes[i] == M_DIM * K_DIM) x    = (const float*)d_in[i];
        else if (in_sizes[i] == N_DIM * K_DIM) W    = (const float*)d_in[i];
        else if (in_sizes[i] == N_DIM)         bias = (const float*)d_in[i];
    }
    if (!x)    x    = (const float*)d_in[0];
    if (!W)    W    = (const float*)d_in[1];
    if (!bias) bias = (const float*)d_in[2];
    float* out = (float*)d_out;

    // workspace layout: counters + worklist only
    const size_t off_cnt = 0;                                   // 128 u32
    const size_t off_wl  = 512;                                 // 128*2048 u32
    const size_t need    = off_wl + (size_t)128 * 2048 * 4;     // ~1.05 MB

    if (ws_size < need) {
        dim3 grid(N_DIM / 64, BATCH);
        lif_openblas_q320<<<grid, 256, 0, stream>>>(x, W, bias, out);
        return;
    }

    char* ws = (char*)d_ws;
    unsigned int* counters = (unsigned int*)(ws + off_cnt);
    unsigned int* worklist = (unsigned int*)(ws + off_wl);

    hipMemsetAsync(counters, 0, 512, stream);   // graph-capturable

    dim3 ggrid(N_DIM / 128, M_DIM / 256);   // (16, 32) -> 512 tiles
    gemm_lif<<<ggrid, 512, 132096, stream>>>(x, W, bias, out, counters, worklist);
    lif_repair2<<<128 * RJ, 256, 0, stream>>>(x, W, bias, counters, worklist, out);
}